// Round 13
// baseline (2806.359 us; speedup 1.0000x reference)
//
#include <hip/hip_runtime.h>
#include <hip/hip_bf16.h>

#define D_MODEL 256
#define N_LAYER 16
#define VOCAB 24
#define D_INNER 512
#define D_STATE 16
#define D_CONV 4
#define DT_RANK 16
#define BATCH 2
#define SEQ 2048
#define NTOK (BATCH*SEQ)   /* 4096 */
#define EPS 1e-5f
#define NC 64              /* scan chunks per sequence */
#define CL (SEQ/NC)        /* 32 tokens per chunk */
#define NSC (BATCH*D_INNER*D_STATE)      /* 16384 scan chains */

typedef __attribute__((ext_vector_type(8))) short short8;
typedef __attribute__((ext_vector_type(4))) float f32x4;

__device__ __forceinline__ float silu(float v) { return v / (1.f + __expf(-v)); }

__device__ __forceinline__ short bfr(float x) {      // f32 -> bf16 RNE
    unsigned u = __float_as_uint(x);
    return (short)((u + 0x7fffu + ((u >> 16) & 1u)) >> 16);
}
__device__ __forceinline__ short8 cvt8(float4 a, float4 b) {
    short8 r;
    r[0] = bfr(a.x); r[1] = bfr(a.y); r[2] = bfr(a.z); r[3] = bfr(a.w);
    r[4] = bfr(b.x); r[5] = bfr(b.y); r[6] = bfr(b.z); r[7] = bfr(b.w);
    return r;
}

// ---------------------------------------------------------------- embedding
__global__ void k_embed(const int* __restrict__ ids, const float* __restrict__ emb,
                        float* __restrict__ residual) {
    int idx = blockIdx.x * 256 + threadIdx.x;      // NTOK*256
    int tok = idx >> 8, c = idx & 255;
    residual[idx] = emb[ids[tok] * D_MODEL + c];
}

// ---------------------------------------------------------------- rmsnorm
__global__ void k_rmsnorm(const float* __restrict__ residual, const float* __restrict__ w,
                          float* __restrict__ hn) {
    __shared__ float red[256];
    int tok = blockIdx.x, c = threadIdx.x;
    float v = residual[tok * 256 + c];
    red[c] = v * v;
    __syncthreads();
    for (int st = 128; st > 0; st >>= 1) {
        if (c < st) red[c] += red[c + st];
        __syncthreads();
    }
    float scale = rsqrtf(red[0] * (1.f / 256.f) + EPS);
    hn[tok * 256 + c] = v * scale * w[c];
}

// ---------------- gemm1 MFMA: [NTOK,256]f32 @ [1024,256]^T f32 -> split x/z
__global__ __launch_bounds__(256) void k_gemm1_mfma(const float* __restrict__ A,
                                                    const float* __restrict__ W,
                                                    float* __restrict__ xh,
                                                    float* __restrict__ zb) {
    __shared__ short AsL[64 * 40];   // [row][40] bf16, pad 32->40
    __shared__ short WsL[64 * 40];
    const int bm = blockIdx.x * 64, bn = blockIdx.y * 64;
    const int tid = threadIdx.x;
    const int wave = tid >> 6, lane = tid & 63;
    const int wm = (wave & 1) * 32, wn = (wave >> 1) * 32;
    const int quad = lane >> 4, lr = lane & 15;
    const int srow = tid >> 2, skq = (tid & 3) * 8;
    f32x4 acc[2][2] = {};
    for (int k0 = 0; k0 < 256; k0 += 32) {
        float4 a0 = *(const float4*)(A + (size_t)(bm + srow) * 256 + k0 + skq);
        float4 a1 = *(const float4*)(A + (size_t)(bm + srow) * 256 + k0 + skq + 4);
        float4 w0 = *(const float4*)(W + (size_t)(bn + srow) * 256 + k0 + skq);
        float4 w1 = *(const float4*)(W + (size_t)(bn + srow) * 256 + k0 + skq + 4);
        __syncthreads();
        *(short8*)&AsL[srow * 40 + skq] = cvt8(a0, a1);
        *(short8*)&WsL[srow * 40 + skq] = cvt8(w0, w1);
        __syncthreads();
        short8 af[2], bf[2];
        #pragma unroll
        for (int i = 0; i < 2; i++) {
            af[i] = *(const short8*)&AsL[(wm + i * 16 + lr) * 40 + quad * 8];
            bf[i] = *(const short8*)&WsL[(wn + i * 16 + lr) * 40 + quad * 8];
        }
        #pragma unroll
        for (int mi = 0; mi < 2; mi++)
            #pragma unroll
            for (int ni = 0; ni < 2; ni++)
                acc[mi][ni] = __builtin_amdgcn_mfma_f32_16x16x32_bf16(
                    af[mi], bf[ni], acc[mi][ni], 0, 0, 0);
    }
    #pragma unroll
    for (int mi = 0; mi < 2; mi++) {
        #pragma unroll
        for (int ni = 0; ni < 2; ni++) {
            int gcol = bn + wn + ni * 16 + lr;
            #pragma unroll
            for (int r = 0; r < 4; r++) {
                int grow = bm + wm + mi * 16 + quad * 4 + r;
                float v = acc[mi][ni][r];
                if (bn < 512) xh[(size_t)grow * 512 + gcol] = v;
                else          zb[(size_t)grow * 512 + gcol - 512] = v;
            }
        }
    }
}

// ---------------- gemm2 MFMA: residual += [NTOK,512] @ [256,512]^T
__global__ __launch_bounds__(256) void k_gemm2_mfma(const float* __restrict__ A,
                                                    const float* __restrict__ W,
                                                    float* __restrict__ residual) {
    __shared__ short AsL[64 * 40];
    __shared__ short WsL[64 * 40];
    const int bm = blockIdx.x * 64, bn = blockIdx.y * 64;
    const int tid = threadIdx.x;
    const int wave = tid >> 6, lane = tid & 63;
    const int wm = (wave & 1) * 32, wn = (wave >> 1) * 32;
    const int quad = lane >> 4, lr = lane & 15;
    const int srow = tid >> 2, skq = (tid & 3) * 8;
    f32x4 acc[2][2] = {};
    for (int k0 = 0; k0 < 512; k0 += 32) {
        float4 a0 = *(const float4*)(A + (size_t)(bm + srow) * 512 + k0 + skq);
        float4 a1 = *(const float4*)(A + (size_t)(bm + srow) * 512 + k0 + skq + 4);
        float4 w0 = *(const float4*)(W + (size_t)(bn + srow) * 512 + k0 + skq);
        float4 w1 = *(const float4*)(W + (size_t)(bn + srow) * 512 + k0 + skq + 4);
        __syncthreads();
        *(short8*)&AsL[srow * 40 + skq] = cvt8(a0, a1);
        *(short8*)&WsL[srow * 40 + skq] = cvt8(w0, w1);
        __syncthreads();
        short8 af[2], bf[2];
        #pragma unroll
        for (int i = 0; i < 2; i++) {
            af[i] = *(const short8*)&AsL[(wm + i * 16 + lr) * 40 + quad * 8];
            bf[i] = *(const short8*)&WsL[(wn + i * 16 + lr) * 40 + quad * 8];
        }
        #pragma unroll
        for (int mi = 0; mi < 2; mi++)
            #pragma unroll
            for (int ni = 0; ni < 2; ni++)
                acc[mi][ni] = __builtin_amdgcn_mfma_f32_16x16x32_bf16(
                    af[mi], bf[ni], acc[mi][ni], 0, 0, 0);
    }
    #pragma unroll
    for (int mi = 0; mi < 2; mi++) {
        #pragma unroll
        for (int ni = 0; ni < 2; ni++) {
            int gcol = bn + wn + ni * 16 + lr;
            #pragma unroll
            for (int r = 0; r < 4; r++) {
                int grow = bm + wm + mi * 16 + quad * 4 + r;
                size_t idx = (size_t)grow * 256 + gcol;
                residual[idx] += acc[mi][ni][r];
            }
        }
    }
}

// ------------- fused depthwise conv + silu + x_proj (4 tokens per block)
// grid 1024 blocks -> ~4 blocks/CU for latency hiding
__global__ __launch_bounds__(256) void k_convxproj(const float* __restrict__ xh,
                                                   const float* __restrict__ cw,
                                                   const float* __restrict__ cb,
                                                   const float* __restrict__ xw,
                                                   float* __restrict__ xb,
                                                   float* __restrict__ dbc) {
    __shared__ __align__(16) float xcS[4][516];    // pad 4
    const int tok0 = blockIdx.x * 4;               // 4 | 2048 -> no batch crossing
    const int b = tok0 >> 11, l0 = tok0 & 2047;
    const int tid = threadIdx.x;
    #pragma unroll
    for (int dstep = 0; dstep < 2; dstep++) {
        int d = tid + dstep * 256;
        float4 cwv = *(const float4*)(cw + d * 4);
        float cbv = cb[d];
        const float* base = xh + ((size_t)(b << 11)) * 512 + d;
        float xv[7];
        #pragma unroll
        for (int i = 0; i < 7; i++) {
            int lt = l0 - 3 + i;
            xv[i] = (lt >= 0) ? base[(size_t)lt * 512] : 0.f;
        }
        #pragma unroll
        for (int t = 0; t < 4; t++) {
            float acc = cbv + xv[t] * cwv.x + xv[t+1] * cwv.y + xv[t+2] * cwv.z + xv[t+3] * cwv.w;
            float v = silu(acc);
            xcS[t][d] = v;
            xb[(size_t)(tok0 + t) * 512 + d] = v;
        }
    }
    __syncthreads();
    const int tokg = tid >> 6, l = tid & 63;       // 64 threads per token
    if (l < 48) {
        const float4* w4 = (const float4*)(xw + (size_t)l * 512);
        const float4* x4 = (const float4*)&xcS[tokg][0];
        float acc = 0.f;
        #pragma unroll 8
        for (int k4 = 0; k4 < 128; k4++) {
            float4 wv = w4[k4];
            float4 xv = x4[k4];
            acc += xv.x * wv.x + xv.y * wv.y + xv.z * wv.z + xv.w * wv.w;
        }
        dbc[(size_t)(tok0 + tokg) * 48 + l] = acc;
    }
}

// -------- scan phase A: 4 threads per chain-chunk, 4 s-states each.
// gid bits: [1:0]=s-group, [11:2]=bd (d fast, then b), [17:12]=chunk
__global__ __launch_bounds__(256) void k_scanA(const float* __restrict__ xb,
                                               const float* __restrict__ dbc,
                                               const float* __restrict__ dtw,
                                               const float* __restrict__ dtb,
                                               const float* __restrict__ a_log,
                                               float* __restrict__ Aprod,
                                               float* __restrict__ Hfin) {
    int gid = blockIdx.x * 256 + threadIdx.x;      // 4*1024*NC = 262144
    int sg = gid & 3;
    int bd = (gid >> 2) & 1023;
    int c = gid >> 12;
    int d = bd & 511, b = bd >> 9;
    float wdt[16];
    #pragma unroll
    for (int q = 0; q < 4; q++)
        *(float4*)&wdt[q*4] = *(const float4*)(dtw + d * 16 + q * 4);
    float4 alq = *(const float4*)(a_log + d * 16 + sg * 4);
    float A[4] = { -__expf(alq.x), -__expf(alq.y), -__expf(alq.z), -__expf(alq.w) };
    float h[4] = {}, ap[4] = {1.f, 1.f, 1.f, 1.f};
    float bdt = dtb[d];
    int tok0 = b * SEQ + c * CL;
    const float* xp = xb + (size_t)tok0 * 512 + d;
    const float* rp = dbc + (size_t)tok0 * 48;
    for (int t = 0; t < CL; t++) {
        float rv[16];
        #pragma unroll
        for (int q = 0; q < 4; q++) *(float4*)&rv[q*4] = *(const float4*)(rp + t * 48 + q * 4);
        float4 Bq = *(const float4*)(rp + t * 48 + 16 + sg * 4);
        float dtr = bdt;
        #pragma unroll
        for (int r = 0; r < 16; r++) dtr = fmaf(rv[r], wdt[r], dtr);
        float dtv = (dtr > 20.f) ? dtr : __logf(1.f + __expf(dtr));
        float u = dtv * xp[t * 512];
        float Bv[4] = {Bq.x, Bq.y, Bq.z, Bq.w};
        #pragma unroll
        for (int s = 0; s < 4; s++) {
            float dA = __expf(dtv * A[s]);
            h[s] = fmaf(dA, h[s], u * Bv[s]);
            ap[s] *= dA;
        }
    }
    size_t base = (size_t)c * NSC + bd * 16 + sg * 4;
    *(float4*)(Aprod + base) = make_float4(ap[0], ap[1], ap[2], ap[3]);
    *(float4*)(Hfin + base)  = make_float4(h[0], h[1], h[2], h[3]);
}

// ---------------- scan phase B: serial combine over chunks (in place)
__global__ void k_scanB(const float* __restrict__ Aprod, float* __restrict__ Hfin) {
    int chain = blockIdx.x * 256 + threadIdx.x;    // NSC
    float h = 0.f;
    for (int c = 0; c < NC; c++) {
        int i = c * NSC + chain;
        float a = Aprod[i], f = Hfin[i];
        Hfin[i] = h;
        h = a * h + f;
    }
}

// -------- scan phase C: rescan from start state; s-sum via 2 shfl_xor
__global__ __launch_bounds__(256) void k_scanC(const float* __restrict__ xb,
                                               const float* __restrict__ zb,
                                               const float* __restrict__ dbc,
                                               const float* __restrict__ dtw,
                                               const float* __restrict__ dtb,
                                               const float* __restrict__ a_log,
                                               const float* __restrict__ Dp,
                                               const float* __restrict__ Hstart,
                                               float* __restrict__ yb) {
    int gid = blockIdx.x * 256 + threadIdx.x;      // 262144
    int sg = gid & 3;
    int bd = (gid >> 2) & 1023;
    int c = gid >> 12;
    int d = bd & 511, b = bd >> 9;
    float wdt[16];
    #pragma unroll
    for (int q = 0; q < 4; q++)
        *(float4*)&wdt[q*4] = *(const float4*)(dtw + d * 16 + q * 4);
    float4 alq = *(const float4*)(a_log + d * 16 + sg * 4);
    float A[4] = { -__expf(alq.x), -__expf(alq.y), -__expf(alq.z), -__expf(alq.w) };
    float4 hq = *(const float4*)(Hstart + (size_t)c * NSC + bd * 16 + sg * 4);
    float h[4] = {hq.x, hq.y, hq.z, hq.w};
    float bdt = dtb[d];
    float Dv = Dp[d];
    int tok0 = b * SEQ + c * CL;
    const float* xp = xb + (size_t)tok0 * 512 + d;
    const float* zp = zb + (size_t)tok0 * 512 + d;
    const float* rp = dbc + (size_t)tok0 * 48;
    float* yp = yb + (size_t)tok0 * 512 + d;
    for (int t = 0; t < CL; t++) {
        float rv[16];
        #pragma unroll
        for (int q = 0; q < 4; q++) *(float4*)&rv[q*4] = *(const float4*)(rp + t * 48 + q * 4);
        float4 Bq = *(const float4*)(rp + t * 48 + 16 + sg * 4);
        float4 Cq = *(const float4*)(rp + t * 48 + 32 + sg * 4);
        float dtr = bdt;
        #pragma unroll
        for (int r = 0; r < 16; r++) dtr = fmaf(rv[r], wdt[r], dtr);
        float dtv = (dtr > 20.f) ? dtr : __logf(1.f + __expf(dtr));
        float xv = xp[t * 512];
        float u = dtv * xv;
        float Bv[4] = {Bq.x, Bq.y, Bq.z, Bq.w};
        float Cv[4] = {Cq.x, Cq.y, Cq.z, Cq.w};
        float sum = 0.f;
        #pragma unroll
        for (int s = 0; s < 4; s++) {
            float dA = __expf(dtv * A[s]);
            h[s] = fmaf(dA, h[s], u * Bv[s]);
            sum = fmaf(h[s], Cv[s], sum);
        }
        sum += __shfl_xor(sum, 1);                 // s-groups live in lane bits 0-1
        sum += __shfl_xor(sum, 2);
        if (sg == 0) {
            float zv = zp[t * 512];
            yp[t * 512] = (sum + Dv * xv) * silu(zv);
        }
    }
}

// ---------------------------------------------------------------- lm head
__global__ void k_head(const float* __restrict__ hn, const float* __restrict__ lw,
                       float* __restrict__ out) {
    int idx = blockIdx.x * 256 + threadIdx.x;      // NTOK*20 = 81920
    int tok = idx / 20, v = idx % 20;
    const float* a = hn + (size_t)tok * 256;
    const float* w = lw + (size_t)v * 256;
    float acc = 0.f;
    for (int k = 0; k < 256; k++) acc += a[k] * w[k];
    out[idx] = acc;
}

extern "C" void kernel_launch(void* const* d_in, const int* in_sizes, int n_in,
                              void* d_out, int out_size, void* d_ws, size_t ws_size,
                              hipStream_t stream) {
    const int*   ids    = (const int*)d_in[0];
    const float* emb    = (const float*)d_in[1];
    const float* in_w   = (const float*)d_in[2];
    const float* conv_w = (const float*)d_in[3];
    const float* conv_b = (const float*)d_in[4];
    const float* x_w    = (const float*)d_in[5];
    const float* dt_w   = (const float*)d_in[6];
    const float* dt_b   = (const float*)d_in[7];
    const float* a_log  = (const float*)d_in[8];
    const float* d_skip = (const float*)d_in[9];
    const float* out_w  = (const float*)d_in[10];
    const float* norm_w = (const float*)d_in[11];
    const float* norm_f = (const float*)d_in[12];
    const float* lm_w   = (const float*)d_in[13];
    float* out = (float*)d_out;

    // ---- workspace: 42,729,472 bytes (r5/r6-proven budget, exact) ----
    char* ws = (char*)d_ws;
    float* residual = (float*)(ws + 0);            // 4 MB
    float* hn       = (float*)(ws + 4194304);      // 4 MB
    float* xh       = (float*)(ws + 8388608);      // 8 MB (aliased: yb after conv)
    float* zb       = (float*)(ws + 16777216);     // 8 MB
    float* xb       = (float*)(ws + 25165824);     // 8 MB
    float* dbc      = (float*)(ws + 33554432);     // 768 KB
    float* Aprod    = (float*)(ws + 34340864);     // NC*NSC f32 = 4 MB
    float* Hfin     = (float*)(ws + 38535168);     // 4 MB -> end 42,729,472
    float* yb       = xh;

    k_embed<<<(NTOK * 256) / 256, 256, 0, stream>>>(ids, emb, residual);

    for (int i = 0; i < N_LAYER; i++) {
        k_rmsnorm<<<NTOK, 256, 0, stream>>>(residual, norm_w + i * D_MODEL, hn);
        dim3 g1(NTOK / 64, 1024 / 64);
        k_gemm1_mfma<<<g1, 256, 0, stream>>>(hn, in_w + (size_t)i * 1024 * 256, xh, zb);
        k_convxproj<<<NTOK / 4, 256, 0, stream>>>(
            xh, conv_w + (size_t)i * 512 * 4, conv_b + (size_t)i * 512,
            x_w + (size_t)i * 48 * 512, xb, dbc);
        k_scanA<<<(4 * 1024 * NC) / 256, 256, 0, stream>>>(
            xb, dbc, dt_w + (size_t)i * 512 * 16, dt_b + (size_t)i * 512,
            a_log + (size_t)i * 512 * 16, Aprod, Hfin);
        k_scanB<<<NSC / 256, 256, 0, stream>>>(Aprod, Hfin);
        k_scanC<<<(4 * 1024 * NC) / 256, 256, 0, stream>>>(
            xb, zb, dbc, dt_w + (size_t)i * 512 * 16, dt_b + (size_t)i * 512,
            a_log + (size_t)i * 512 * 16, d_skip + (size_t)i * 512, Hfin, yb);
        dim3 g2(NTOK / 64, 256 / 64);
        k_gemm2_mfma<<<g2, 256, 0, stream>>>(yb, out_w + (size_t)i * 256 * 512, residual);
    }

    k_rmsnorm<<<NTOK, 256, 0, stream>>>(residual, norm_f, hn);
    k_head<<<320, 256, 0, stream>>>(hn, lm_w, out);
}

// Round 14
// 1900.194 us; speedup vs baseline: 1.4769x; 1.4769x over previous
//
#include <hip/hip_runtime.h>
#include <hip/hip_bf16.h>

#define D_MODEL 256
#define N_LAYER 16
#define VOCAB 24
#define D_INNER 512
#define D_STATE 16
#define D_CONV 4
#define DT_RANK 16
#define BATCH 2
#define SEQ 2048
#define NTOK (BATCH*SEQ)   /* 4096 */
#define EPS 1e-5f
#define NC 64              /* scan chunks per sequence */
#define CL (SEQ/NC)        /* 32 tokens per chunk */
#define NSC (BATCH*D_INNER*D_STATE)      /* 16384 scan chains */

typedef __attribute__((ext_vector_type(8))) short short8;
typedef __attribute__((ext_vector_type(4))) float f32x4;

__device__ __forceinline__ float silu(float v) { return v / (1.f + __expf(-v)); }

__device__ __forceinline__ short bfr(float x) {      // f32 -> bf16 RNE
    unsigned u = __float_as_uint(x);
    return (short)((u + 0x7fffu + ((u >> 16) & 1u)) >> 16);
}
__device__ __forceinline__ short8 cvt8(float4 a, float4 b) {
    short8 r;
    r[0] = bfr(a.x); r[1] = bfr(a.y); r[2] = bfr(a.z); r[3] = bfr(a.w);
    r[4] = bfr(b.x); r[5] = bfr(b.y); r[6] = bfr(b.z); r[7] = bfr(b.w);
    return r;
}

// ---------------------------------------------------------------- embedding
__global__ void k_embed(const int* __restrict__ ids, const float* __restrict__ emb,
                        float* __restrict__ residual) {
    int idx = blockIdx.x * 256 + threadIdx.x;      // NTOK*256
    int tok = idx >> 8, c = idx & 255;
    residual[idx] = emb[ids[tok] * D_MODEL + c];
}

// ---------------------------------------------------------------- rmsnorm
__global__ void k_rmsnorm(const float* __restrict__ residual, const float* __restrict__ w,
                          float* __restrict__ hn) {
    __shared__ float red[256];
    int tok = blockIdx.x, c = threadIdx.x;
    float v = residual[tok * 256 + c];
    red[c] = v * v;
    __syncthreads();
    for (int st = 128; st > 0; st >>= 1) {
        if (c < st) red[c] += red[c + st];
        __syncthreads();
    }
    float scale = rsqrtf(red[0] * (1.f / 256.f) + EPS);
    hn[tok * 256 + c] = v * scale * w[c];
}

// ---------------- gemm1 MFMA: [NTOK,256]f32 @ [1024,256]^T f32 -> split x/z
__global__ __launch_bounds__(256) void k_gemm1_mfma(const float* __restrict__ A,
                                                    const float* __restrict__ W,
                                                    float* __restrict__ xh,
                                                    float* __restrict__ zb) {
    __shared__ short AsL[64 * 40];   // [row][40] bf16, pad 32->40
    __shared__ short WsL[64 * 40];
    const int bm = blockIdx.x * 64, bn = blockIdx.y * 64;
    const int tid = threadIdx.x;
    const int wave = tid >> 6, lane = tid & 63;
    const int wm = (wave & 1) * 32, wn = (wave >> 1) * 32;
    const int quad = lane >> 4, lr = lane & 15;
    const int srow = tid >> 2, skq = (tid & 3) * 8;
    f32x4 acc[2][2] = {};
    for (int k0 = 0; k0 < 256; k0 += 32) {
        float4 a0 = *(const float4*)(A + (size_t)(bm + srow) * 256 + k0 + skq);
        float4 a1 = *(const float4*)(A + (size_t)(bm + srow) * 256 + k0 + skq + 4);
        float4 w0 = *(const float4*)(W + (size_t)(bn + srow) * 256 + k0 + skq);
        float4 w1 = *(const float4*)(W + (size_t)(bn + srow) * 256 + k0 + skq + 4);
        __syncthreads();
        *(short8*)&AsL[srow * 40 + skq] = cvt8(a0, a1);
        *(short8*)&WsL[srow * 40 + skq] = cvt8(w0, w1);
        __syncthreads();
        short8 af[2], bf[2];
        #pragma unroll
        for (int i = 0; i < 2; i++) {
            af[i] = *(const short8*)&AsL[(wm + i * 16 + lr) * 40 + quad * 8];
            bf[i] = *(const short8*)&WsL[(wn + i * 16 + lr) * 40 + quad * 8];
        }
        #pragma unroll
        for (int mi = 0; mi < 2; mi++)
            #pragma unroll
            for (int ni = 0; ni < 2; ni++)
                acc[mi][ni] = __builtin_amdgcn_mfma_f32_16x16x32_bf16(
                    af[mi], bf[ni], acc[mi][ni], 0, 0, 0);
    }
    #pragma unroll
    for (int mi = 0; mi < 2; mi++) {
        #pragma unroll
        for (int ni = 0; ni < 2; ni++) {
            int gcol = bn + wn + ni * 16 + lr;
            #pragma unroll
            for (int r = 0; r < 4; r++) {
                int grow = bm + wm + mi * 16 + quad * 4 + r;
                float v = acc[mi][ni][r];
                if (bn < 512) xh[(size_t)grow * 512 + gcol] = v;
                else          zb[(size_t)grow * 512 + gcol - 512] = v;
            }
        }
    }
}

// ---------------- gemm2 MFMA: residual += [NTOK,512] @ [256,512]^T
__global__ __launch_bounds__(256) void k_gemm2_mfma(const float* __restrict__ A,
                                                    const float* __restrict__ W,
                                                    float* __restrict__ residual) {
    __shared__ short AsL[64 * 40];
    __shared__ short WsL[64 * 40];
    const int bm = blockIdx.x * 64, bn = blockIdx.y * 64;
    const int tid = threadIdx.x;
    const int wave = tid >> 6, lane = tid & 63;
    const int wm = (wave & 1) * 32, wn = (wave >> 1) * 32;
    const int quad = lane >> 4, lr = lane & 15;
    const int srow = tid >> 2, skq = (tid & 3) * 8;
    f32x4 acc[2][2] = {};
    for (int k0 = 0; k0 < 512; k0 += 32) {
        float4 a0 = *(const float4*)(A + (size_t)(bm + srow) * 512 + k0 + skq);
        float4 a1 = *(const float4*)(A + (size_t)(bm + srow) * 512 + k0 + skq + 4);
        float4 w0 = *(const float4*)(W + (size_t)(bn + srow) * 512 + k0 + skq);
        float4 w1 = *(const float4*)(W + (size_t)(bn + srow) * 512 + k0 + skq + 4);
        __syncthreads();
        *(short8*)&AsL[srow * 40 + skq] = cvt8(a0, a1);
        *(short8*)&WsL[srow * 40 + skq] = cvt8(w0, w1);
        __syncthreads();
        short8 af[2], bf[2];
        #pragma unroll
        for (int i = 0; i < 2; i++) {
            af[i] = *(const short8*)&AsL[(wm + i * 16 + lr) * 40 + quad * 8];
            bf[i] = *(const short8*)&WsL[(wn + i * 16 + lr) * 40 + quad * 8];
        }
        #pragma unroll
        for (int mi = 0; mi < 2; mi++)
            #pragma unroll
            for (int ni = 0; ni < 2; ni++)
                acc[mi][ni] = __builtin_amdgcn_mfma_f32_16x16x32_bf16(
                    af[mi], bf[ni], acc[mi][ni], 0, 0, 0);
    }
    #pragma unroll
    for (int mi = 0; mi < 2; mi++) {
        #pragma unroll
        for (int ni = 0; ni < 2; ni++) {
            int gcol = bn + wn + ni * 16 + lr;
            #pragma unroll
            for (int r = 0; r < 4; r++) {
                int grow = bm + wm + mi * 16 + quad * 4 + r;
                size_t idx = (size_t)grow * 256 + gcol;
                residual[idx] += acc[mi][ni][r];
            }
        }
    }
}

// ---------------- depthwise conv + silu: thread = (d, 4 consecutive tokens)
// d-fast indexing -> coalesced; 7 loads / 4 stores per thread
__global__ void k_conv(const float* __restrict__ xh, const float* __restrict__ cw,
                       const float* __restrict__ cb, float* __restrict__ xb) {
    int gid = blockIdx.x * 256 + threadIdx.x;      // 512 * NTOK/4 = 524288
    int d = gid & 511;
    int tq = gid >> 9;                             // 0..1023
    int tok0 = tq * 4;                             // 4 | 2048: no batch crossing
    int b = tok0 >> 11, l0 = tok0 & 2047;
    float4 cwv = *(const float4*)(cw + d * 4);
    float cbv = cb[d];
    const float* base = xh + ((size_t)(b << 11)) * 512 + d;
    float xv[7];
    #pragma unroll
    for (int i = 0; i < 7; i++) {
        int lt = l0 - 3 + i;
        xv[i] = (lt >= 0) ? base[(size_t)lt * 512] : 0.f;
    }
    float* dst = xb + (size_t)tok0 * 512 + d;
    #pragma unroll
    for (int t = 0; t < 4; t++) {
        float acc = cbv + xv[t] * cwv.x + xv[t+1] * cwv.y + xv[t+2] * cwv.z + xv[t+3] * cwv.w;
        dst[(size_t)t * 512] = silu(acc);
    }
}

// ---------------- x_proj MFMA: dbc[NTOK,48] = xc[NTOK,512] @ xw[48,512]^T
// N padded to 64; B rows 48..63 uninitialized -> pollute only discarded cols
__global__ __launch_bounds__(256) void k_xproj_mfma(const float* __restrict__ A,
                                                    const float* __restrict__ W,
                                                    float* __restrict__ dbc) {
    __shared__ short AsL[64 * 40];
    __shared__ short WsL[64 * 40];
    const int bm = blockIdx.x * 64;
    const int tid = threadIdx.x;
    const int wave = tid >> 6, lane = tid & 63;
    const int wm = (wave & 1) * 32, wn = (wave >> 1) * 32;
    const int quad = lane >> 4, lr = lane & 15;
    const int srow = tid >> 2, skq = (tid & 3) * 8;
    f32x4 acc[2][2] = {};
    for (int k0 = 0; k0 < 512; k0 += 32) {
        float4 a0 = *(const float4*)(A + (size_t)(bm + srow) * 512 + k0 + skq);
        float4 a1 = *(const float4*)(A + (size_t)(bm + srow) * 512 + k0 + skq + 4);
        float4 w0, w1;
        if (srow < 48) {
            w0 = *(const float4*)(W + (size_t)srow * 512 + k0 + skq);
            w1 = *(const float4*)(W + (size_t)srow * 512 + k0 + skq + 4);
        }
        __syncthreads();
        *(short8*)&AsL[srow * 40 + skq] = cvt8(a0, a1);
        if (srow < 48) *(short8*)&WsL[srow * 40 + skq] = cvt8(w0, w1);
        __syncthreads();
        short8 af[2], bf[2];
        #pragma unroll
        for (int i = 0; i < 2; i++) {
            af[i] = *(const short8*)&AsL[(wm + i * 16 + lr) * 40 + quad * 8];
            bf[i] = *(const short8*)&WsL[(wn + i * 16 + lr) * 40 + quad * 8];
        }
        #pragma unroll
        for (int mi = 0; mi < 2; mi++)
            #pragma unroll
            for (int ni = 0; ni < 2; ni++)
                acc[mi][ni] = __builtin_amdgcn_mfma_f32_16x16x32_bf16(
                    af[mi], bf[ni], acc[mi][ni], 0, 0, 0);
    }
    #pragma unroll
    for (int mi = 0; mi < 2; mi++) {
        #pragma unroll
        for (int ni = 0; ni < 2; ni++) {
            int gcol = wn + ni * 16 + lr;
            if (gcol < 48) {
                #pragma unroll
                for (int r = 0; r < 4; r++) {
                    int grow = bm + wm + mi * 16 + quad * 4 + r;
                    dbc[(size_t)grow * 48 + gcol] = acc[mi][ni][r];
                }
            }
        }
    }
}

// -------- scan phase A: thread = (b,d,chunk); dt fused; 16 s-states in regs
__global__ __launch_bounds__(64) void k_scanA(const float* __restrict__ xb,
                                              const float* __restrict__ dbc,
                                              const float* __restrict__ dtw,
                                              const float* __restrict__ dtb,
                                              const float* __restrict__ a_log,
                                              float* __restrict__ Aprod,
                                              float* __restrict__ Hfin) {
    int gid = blockIdx.x * 64 + threadIdx.x;       // 1024*NC = 65536
    int bd = gid & 1023;
    int c = gid >> 10;
    int d = bd & 511, b = bd >> 9;
    float A[16], h[16], ap[16], wdt[16];
    #pragma unroll
    for (int q = 0; q < 4; q++)
        *(float4*)&wdt[q*4] = *(const float4*)(dtw + d * 16 + q * 4);
    #pragma unroll
    for (int s = 0; s < 16; s++) {
        A[s] = -__expf(a_log[d * 16 + s]);
        h[s] = 0.f; ap[s] = 1.f;
    }
    float bdt = dtb[d];
    int tok0 = b * SEQ + c * CL;
    const float* xp = xb + (size_t)tok0 * 512 + d;
    const float* rp = dbc + (size_t)tok0 * 48;
    for (int t = 0; t < CL; t++) {
        float rv[32];
        #pragma unroll
        for (int q = 0; q < 8; q++) *(float4*)&rv[q*4] = *(const float4*)(rp + t * 48 + q * 4);
        float dtr = bdt;
        #pragma unroll
        for (int r = 0; r < 16; r++) dtr = fmaf(rv[r], wdt[r], dtr);
        float dtv = (dtr > 20.f) ? dtr : __logf(1.f + __expf(dtr));
        float u = dtv * xp[t * 512];
        #pragma unroll
        for (int s = 0; s < 16; s++) {
            float dA = __expf(dtv * A[s]);
            h[s] = fmaf(dA, h[s], u * rv[16 + s]);
            ap[s] *= dA;
        }
    }
    float* Ap = Aprod + (size_t)c * NSC + bd * 16;
    float* Hp = Hfin  + (size_t)c * NSC + bd * 16;
    #pragma unroll
    for (int q = 0; q < 4; q++) {
        *(float4*)(Ap + q * 4) = make_float4(ap[q*4], ap[q*4+1], ap[q*4+2], ap[q*4+3]);
        *(float4*)(Hp + q * 4) = make_float4(h[q*4], h[q*4+1], h[q*4+2], h[q*4+3]);
    }
}

// ---------------- scan phase B: serial combine over chunks (in place)
__global__ void k_scanB(const float* __restrict__ Aprod, float* __restrict__ Hfin) {
    int chain = blockIdx.x * 256 + threadIdx.x;    // NSC
    float h = 0.f;
    for (int c = 0; c < NC; c++) {
        int i = c * NSC + chain;
        float a = Aprod[i], f = Hfin[i];
        Hfin[i] = h;
        h = a * h + f;
    }
}

// -------- scan phase C: rescan from start state (dt fused), gate -> y
__global__ __launch_bounds__(64) void k_scanC(const float* __restrict__ xb,
                                              const float* __restrict__ zb,
                                              const float* __restrict__ dbc,
                                              const float* __restrict__ dtw,
                                              const float* __restrict__ dtb,
                                              const float* __restrict__ a_log,
                                              const float* __restrict__ Dp,
                                              const float* __restrict__ Hstart,
                                              float* __restrict__ yb) {
    int gid = blockIdx.x * 64 + threadIdx.x;       // 65536
    int bd = gid & 1023;
    int c = gid >> 10;
    int d = bd & 511, b = bd >> 9;
    float A[16], h[16], wdt[16];
    #pragma unroll
    for (int q = 0; q < 4; q++)
        *(float4*)&wdt[q*4] = *(const float4*)(dtw + d * 16 + q * 4);
    const float* Hp = Hstart + (size_t)c * NSC + bd * 16;
    #pragma unroll
    for (int s = 0; s < 16; s++) {
        A[s] = -__expf(a_log[d * 16 + s]);
        h[s] = Hp[s];
    }
    float bdt = dtb[d];
    float Dv = Dp[d];
    int tok0 = b * SEQ + c * CL;
    const float* xp = xb + (size_t)tok0 * 512 + d;
    const float* zp = zb + (size_t)tok0 * 512 + d;
    const float* rp = dbc + (size_t)tok0 * 48;
    float* yp = yb + (size_t)tok0 * 512 + d;
    for (int t = 0; t < CL; t++) {
        float rv[48];
        #pragma unroll
        for (int q = 0; q < 12; q++) *(float4*)&rv[q*4] = *(const float4*)(rp + t * 48 + q * 4);
        float dtr = bdt;
        #pragma unroll
        for (int r = 0; r < 16; r++) dtr = fmaf(rv[r], wdt[r], dtr);
        float dtv = (dtr > 20.f) ? dtr : __logf(1.f + __expf(dtr));
        float xv = xp[t * 512];
        float u = dtv * xv;
        float sum = 0.f;
        #pragma unroll
        for (int s = 0; s < 16; s++) {
            float dA = __expf(dtv * A[s]);
            h[s] = fmaf(dA, h[s], u * rv[16 + s]);
            sum = fmaf(h[s], rv[32 + s], sum);
        }
        float zv = zp[t * 512];
        yp[t * 512] = (sum + Dv * xv) * silu(zv);
    }
}

// ---------------------------------------------------------------- lm head
__global__ void k_head(const float* __restrict__ hn, const float* __restrict__ lw,
                       float* __restrict__ out) {
    int idx = blockIdx.x * 256 + threadIdx.x;      // NTOK*20 = 81920
    int tok = idx / 20, v = idx % 20;
    const float* a = hn + (size_t)tok * 256;
    const float* w = lw + (size_t)v * 256;
    float acc = 0.f;
    for (int k = 0; k < 256; k++) acc += a[k] * w[k];
    out[idx] = acc;
}

extern "C" void kernel_launch(void* const* d_in, const int* in_sizes, int n_in,
                              void* d_out, int out_size, void* d_ws, size_t ws_size,
                              hipStream_t stream) {
    const int*   ids    = (const int*)d_in[0];
    const float* emb    = (const float*)d_in[1];
    const float* in_w   = (const float*)d_in[2];
    const float* conv_w = (const float*)d_in[3];
    const float* conv_b = (const float*)d_in[4];
    const float* x_w    = (const float*)d_in[5];
    const float* dt_w   = (const float*)d_in[6];
    const float* dt_b   = (const float*)d_in[7];
    const float* a_log  = (const float*)d_in[8];
    const float* d_skip = (const float*)d_in[9];
    const float* out_w  = (const float*)d_in[10];
    const float* norm_w = (const float*)d_in[11];
    const float* norm_f = (const float*)d_in[12];
    const float* lm_w   = (const float*)d_in[13];
    float* out = (float*)d_out;

    // ---- workspace: 42,729,472 bytes (r5/r6-proven budget, exact) ----
    char* ws = (char*)d_ws;
    float* residual = (float*)(ws + 0);            // 4 MB
    float* hn       = (float*)(ws + 4194304);      // 4 MB
    float* xh       = (float*)(ws + 8388608);      // 8 MB (aliased: yb after conv)
    float* zb       = (float*)(ws + 16777216);     // 8 MB
    float* xb       = (float*)(ws + 25165824);     // 8 MB
    float* dbc      = (float*)(ws + 33554432);     // 768 KB
    float* Aprod    = (float*)(ws + 34340864);     // NC*NSC f32 = 4 MB
    float* Hfin     = (float*)(ws + 38535168);     // 4 MB -> end 42,729,472
    float* yb       = xh;

    k_embed<<<(NTOK * 256) / 256, 256, 0, stream>>>(ids, emb, residual);

    for (int i = 0; i < N_LAYER; i++) {
        k_rmsnorm<<<NTOK, 256, 0, stream>>>(residual, norm_w + i * D_MODEL, hn);
        dim3 g1(NTOK / 64, 1024 / 64);
        k_gemm1_mfma<<<g1, 256, 0, stream>>>(hn, in_w + (size_t)i * 1024 * 256, xh, zb);
        k_conv<<<(512 * NTOK / 4) / 256, 256, 0, stream>>>(
            xh, conv_w + (size_t)i * 512 * 4, conv_b + (size_t)i * 512, xb);
        k_xproj_mfma<<<NTOK / 64, 256, 0, stream>>>(
            xb, x_w + (size_t)i * 48 * 512, dbc);
        k_scanA<<<(1024 * NC) / 64, 64, 0, stream>>>(
            xb, dbc, dt_w + (size_t)i * 512 * 16, dt_b + (size_t)i * 512,
            a_log + (size_t)i * 512 * 16, Aprod, Hfin);
        k_scanB<<<NSC / 256, 256, 0, stream>>>(Aprod, Hfin);
        k_scanC<<<(1024 * NC) / 64, 64, 0, stream>>>(
            xb, zb, dbc, dt_w + (size_t)i * 512 * 16, dt_b + (size_t)i * 512,
            a_log + (size_t)i * 512 * 16, d_skip + (size_t)i * 512, Hfin, yb);
        dim3 g2(NTOK / 64, 256 / 64);
        k_gemm2_mfma<<<g2, 256, 0, stream>>>(yb, out_w + (size_t)i * 256 * 512, residual);
    }

    k_rmsnorm<<<NTOK, 256, 0, stream>>>(residual, norm_f, hn);
    k_head<<<320, 256, 0, stream>>>(hn, lm_w, out);
}

// Round 15
// 1754.074 us; speedup vs baseline: 1.5999x; 1.0833x over previous
//
#include <hip/hip_runtime.h>
#include <hip/hip_bf16.h>

#define D_MODEL 256
#define N_LAYER 16
#define VOCAB 24
#define D_INNER 512
#define D_STATE 16
#define D_CONV 4
#define DT_RANK 16
#define BATCH 2
#define SEQ 2048
#define NTOK (BATCH*SEQ)   /* 4096 */
#define EPS 1e-5f
#define NC 128             /* scan chunks per sequence */
#define CL (SEQ/NC)        /* 16 tokens per chunk */
#define NSC (BATCH*D_INNER*D_STATE)      /* 16384 scan chains */

typedef __hip_bfloat16 bf16;
typedef __attribute__((ext_vector_type(8))) short short8;
typedef __attribute__((ext_vector_type(4))) float f32x4;

__device__ __forceinline__ float silu(float v) { return v / (1.f + __expf(-v)); }
__device__ __forceinline__ float bf2f(bf16 v) { return __bfloat162float(v); }

__device__ __forceinline__ short bfr(float x) {      // f32 -> bf16 RNE
    unsigned u = __float_as_uint(x);
    return (short)((u + 0x7fffu + ((u >> 16) & 1u)) >> 16);
}
__device__ __forceinline__ short8 cvt8(float4 a, float4 b) {
    short8 r;
    r[0] = bfr(a.x); r[1] = bfr(a.y); r[2] = bfr(a.z); r[3] = bfr(a.w);
    r[4] = bfr(b.x); r[5] = bfr(b.y); r[6] = bfr(b.z); r[7] = bfr(b.w);
    return r;
}

// ---------------------------------------------------------------- embedding
__global__ void k_embed(const int* __restrict__ ids, const float* __restrict__ emb,
                        float* __restrict__ residual) {
    int idx = blockIdx.x * 256 + threadIdx.x;      // NTOK*256
    int tok = idx >> 8, c = idx & 255;
    residual[idx] = emb[ids[tok] * D_MODEL + c];
}

// ---------------------------------------------------------------- rmsnorm
__global__ void k_rmsnorm(const float* __restrict__ residual, const float* __restrict__ w,
                          float* __restrict__ hn) {
    __shared__ float red[256];
    int tok = blockIdx.x, c = threadIdx.x;
    float v = residual[tok * 256 + c];
    red[c] = v * v;
    __syncthreads();
    for (int st = 128; st > 0; st >>= 1) {
        if (c < st) red[c] += red[c + st];
        __syncthreads();
    }
    float scale = rsqrtf(red[0] * (1.f / 256.f) + EPS);
    hn[tok * 256 + c] = v * scale * w[c];
}

// ---------------- gemm1 MFMA: [NTOK,256]f32 @ [1024,256]^T f32
//                  -> xh (f32, cols<512) and zb (bf16, cols>=512)
__global__ __launch_bounds__(256) void k_gemm1_mfma(const float* __restrict__ A,
                                                    const float* __restrict__ W,
                                                    float* __restrict__ xh,
                                                    bf16* __restrict__ zb) {
    __shared__ short AsL[64 * 40];   // [row][40] bf16, pad 32->40
    __shared__ short WsL[64 * 40];
    const int bm = blockIdx.x * 64, bn = blockIdx.y * 64;
    const int tid = threadIdx.x;
    const int wave = tid >> 6, lane = tid & 63;
    const int wm = (wave & 1) * 32, wn = (wave >> 1) * 32;
    const int quad = lane >> 4, lr = lane & 15;
    const int srow = tid >> 2, skq = (tid & 3) * 8;
    f32x4 acc[2][2] = {};
    for (int k0 = 0; k0 < 256; k0 += 32) {
        float4 a0 = *(const float4*)(A + (size_t)(bm + srow) * 256 + k0 + skq);
        float4 a1 = *(const float4*)(A + (size_t)(bm + srow) * 256 + k0 + skq + 4);
        float4 w0 = *(const float4*)(W + (size_t)(bn + srow) * 256 + k0 + skq);
        float4 w1 = *(const float4*)(W + (size_t)(bn + srow) * 256 + k0 + skq + 4);
        __syncthreads();
        *(short8*)&AsL[srow * 40 + skq] = cvt8(a0, a1);
        *(short8*)&WsL[srow * 40 + skq] = cvt8(w0, w1);
        __syncthreads();
        short8 af[2], bf[2];
        #pragma unroll
        for (int i = 0; i < 2; i++) {
            af[i] = *(const short8*)&AsL[(wm + i * 16 + lr) * 40 + quad * 8];
            bf[i] = *(const short8*)&WsL[(wn + i * 16 + lr) * 40 + quad * 8];
        }
        #pragma unroll
        for (int mi = 0; mi < 2; mi++)
            #pragma unroll
            for (int ni = 0; ni < 2; ni++)
                acc[mi][ni] = __builtin_amdgcn_mfma_f32_16x16x32_bf16(
                    af[mi], bf[ni], acc[mi][ni], 0, 0, 0);
    }
    #pragma unroll
    for (int mi = 0; mi < 2; mi++) {
        #pragma unroll
        for (int ni = 0; ni < 2; ni++) {
            int gcol = bn + wn + ni * 16 + lr;
            #pragma unroll
            for (int r = 0; r < 4; r++) {
                int grow = bm + wm + mi * 16 + quad * 4 + r;
                float v = acc[mi][ni][r];
                if (bn < 512) xh[(size_t)grow * 512 + gcol] = v;       // uniform branch
                else          zb[(size_t)grow * 512 + gcol - 512] = __float2bfloat16(v);
            }
        }
    }
}

// ---------------- gemm2 MFMA: residual += [NTOK,512]f32 @ [256,512]^T
__global__ __launch_bounds__(256) void k_gemm2_mfma(const float* __restrict__ A,
                                                    const float* __restrict__ W,
                                                    float* __restrict__ residual) {
    __shared__ short AsL[64 * 40];
    __shared__ short WsL[64 * 40];
    const int bm = blockIdx.x * 64, bn = blockIdx.y * 64;
    const int tid = threadIdx.x;
    const int wave = tid >> 6, lane = tid & 63;
    const int wm = (wave & 1) * 32, wn = (wave >> 1) * 32;
    const int quad = lane >> 4, lr = lane & 15;
    const int srow = tid >> 2, skq = (tid & 3) * 8;
    f32x4 acc[2][2] = {};
    for (int k0 = 0; k0 < 512; k0 += 32) {
        float4 a0 = *(const float4*)(A + (size_t)(bm + srow) * 512 + k0 + skq);
        float4 a1 = *(const float4*)(A + (size_t)(bm + srow) * 512 + k0 + skq + 4);
        float4 w0 = *(const float4*)(W + (size_t)(bn + srow) * 512 + k0 + skq);
        float4 w1 = *(const float4*)(W + (size_t)(bn + srow) * 512 + k0 + skq + 4);
        __syncthreads();
        *(short8*)&AsL[srow * 40 + skq] = cvt8(a0, a1);
        *(short8*)&WsL[srow * 40 + skq] = cvt8(w0, w1);
        __syncthreads();
        short8 af[2], bf[2];
        #pragma unroll
        for (int i = 0; i < 2; i++) {
            af[i] = *(const short8*)&AsL[(wm + i * 16 + lr) * 40 + quad * 8];
            bf[i] = *(const short8*)&WsL[(wn + i * 16 + lr) * 40 + quad * 8];
        }
        #pragma unroll
        for (int mi = 0; mi < 2; mi++)
            #pragma unroll
            for (int ni = 0; ni < 2; ni++)
                acc[mi][ni] = __builtin_amdgcn_mfma_f32_16x16x32_bf16(
                    af[mi], bf[ni], acc[mi][ni], 0, 0, 0);
    }
    #pragma unroll
    for (int mi = 0; mi < 2; mi++) {
        #pragma unroll
        for (int ni = 0; ni < 2; ni++) {
            int gcol = bn + wn + ni * 16 + lr;
            #pragma unroll
            for (int r = 0; r < 4; r++) {
                int grow = bm + wm + mi * 16 + quad * 4 + r;
                size_t idx = (size_t)grow * 256 + gcol;
                residual[idx] += acc[mi][ni][r];
            }
        }
    }
}

// ---------------- depthwise conv + silu: thread = (d, 4 consecutive tokens)
__global__ void k_conv(const float* __restrict__ xh, const float* __restrict__ cw,
                       const float* __restrict__ cb, bf16* __restrict__ xb) {
    int gid = blockIdx.x * 256 + threadIdx.x;      // 512 * NTOK/4 = 524288
    int d = gid & 511;
    int tq = gid >> 9;                             // 0..1023
    int tok0 = tq * 4;                             // 4 | 2048: no batch crossing
    int b = tok0 >> 11, l0 = tok0 & 2047;
    float4 cwv = *(const float4*)(cw + d * 4);
    float cbv = cb[d];
    const float* base = xh + ((size_t)(b << 11)) * 512 + d;
    float xv[7];
    #pragma unroll
    for (int i = 0; i < 7; i++) {
        int lt = l0 - 3 + i;
        xv[i] = (lt >= 0) ? base[(size_t)lt * 512] : 0.f;
    }
    bf16* dst = xb + (size_t)tok0 * 512 + d;
    #pragma unroll
    for (int t = 0; t < 4; t++) {
        float acc = cbv + xv[t] * cwv.x + xv[t+1] * cwv.y + xv[t+2] * cwv.z + xv[t+3] * cwv.w;
        dst[(size_t)t * 512] = __float2bfloat16(silu(acc));
    }
}

// ---------------- x_proj MFMA: dbc[NTOK,48] = xc[NTOK,512]bf16 @ xw[48,512]^T
__global__ __launch_bounds__(256) void k_xproj_mfma(const bf16* __restrict__ Abf,
                                                    const float* __restrict__ W,
                                                    float* __restrict__ dbc) {
    __shared__ short AsL[64 * 40];
    __shared__ short WsL[64 * 40];
    const short* A16 = (const short*)Abf;
    const int bm = blockIdx.x * 64;
    const int tid = threadIdx.x;
    const int wave = tid >> 6, lane = tid & 63;
    const int wm = (wave & 1) * 32, wn = (wave >> 1) * 32;
    const int quad = lane >> 4, lr = lane & 15;
    const int srow = tid >> 2, skq = (tid & 3) * 8;
    f32x4 acc[2][2] = {};
    for (int k0 = 0; k0 < 512; k0 += 32) {
        short8 a8 = *(const short8*)(A16 + (size_t)(bm + srow) * 512 + k0 + skq);
        float4 w0, w1;
        if (srow < 48) {
            w0 = *(const float4*)(W + (size_t)srow * 512 + k0 + skq);
            w1 = *(const float4*)(W + (size_t)srow * 512 + k0 + skq + 4);
        }
        __syncthreads();
        *(short8*)&AsL[srow * 40 + skq] = a8;
        if (srow < 48) *(short8*)&WsL[srow * 40 + skq] = cvt8(w0, w1);
        __syncthreads();
        short8 af[2], bf[2];
        #pragma unroll
        for (int i = 0; i < 2; i++) {
            af[i] = *(const short8*)&AsL[(wm + i * 16 + lr) * 40 + quad * 8];
            bf[i] = *(const short8*)&WsL[(wn + i * 16 + lr) * 40 + quad * 8];
        }
        #pragma unroll
        for (int mi = 0; mi < 2; mi++)
            #pragma unroll
            for (int ni = 0; ni < 2; ni++)
                acc[mi][ni] = __builtin_amdgcn_mfma_f32_16x16x32_bf16(
                    af[mi], bf[ni], acc[mi][ni], 0, 0, 0);
    }
    #pragma unroll
    for (int mi = 0; mi < 2; mi++) {
        #pragma unroll
        for (int ni = 0; ni < 2; ni++) {
            int gcol = wn + ni * 16 + lr;
            if (gcol < 48) {
                #pragma unroll
                for (int r = 0; r < 4; r++) {
                    int grow = bm + wm + mi * 16 + quad * 4 + r;
                    dbc[(size_t)grow * 48 + gcol] = acc[mi][ni][r];
                }
            }
        }
    }
}

// -------- scan phase A: thread = (b,d,chunk); dt fused; 16 s-states in regs
__global__ __launch_bounds__(64) void k_scanA(const bf16* __restrict__ xb,
                                              const float* __restrict__ dbc,
                                              const float* __restrict__ dtw,
                                              const float* __restrict__ dtb,
                                              const float* __restrict__ a_log,
                                              float* __restrict__ Aprod,
                                              float* __restrict__ Hfin) {
    int gid = blockIdx.x * 64 + threadIdx.x;       // 1024*NC = 131072
    int bd = gid & 1023;                           // d fast -> coalesced
    int c = gid >> 10;
    int d = bd & 511, b = bd >> 9;
    float A[16], h[16], ap[16], wdt[16];
    #pragma unroll
    for (int q = 0; q < 4; q++)
        *(float4*)&wdt[q*4] = *(const float4*)(dtw + d * 16 + q * 4);
    #pragma unroll
    for (int s = 0; s < 16; s++) {
        A[s] = -__expf(a_log[d * 16 + s]);
        h[s] = 0.f; ap[s] = 1.f;
    }
    float bdt = dtb[d];
    int tok0 = b * SEQ + c * CL;
    const bf16* xp = xb + (size_t)tok0 * 512 + d;
    const float* rp = dbc + (size_t)tok0 * 48;
    for (int t = 0; t < CL; t++) {
        float rv[32];
        #pragma unroll
        for (int q = 0; q < 8; q++) *(float4*)&rv[q*4] = *(const float4*)(rp + t * 48 + q * 4);
        float dtr = bdt;
        #pragma unroll
        for (int r = 0; r < 16; r++) dtr = fmaf(rv[r], wdt[r], dtr);
        float dtv = (dtr > 20.f) ? dtr : __logf(1.f + __expf(dtr));
        float u = dtv * bf2f(xp[t * 512]);
        #pragma unroll
        for (int s = 0; s < 16; s++) {
            float dA = __expf(dtv * A[s]);
            h[s] = fmaf(dA, h[s], u * rv[16 + s]);
            ap[s] *= dA;
        }
    }
    float* Ap = Aprod + (size_t)c * NSC + bd * 16;
    float* Hp = Hfin  + (size_t)c * NSC + bd * 16;
    #pragma unroll
    for (int q = 0; q < 4; q++) {
        *(float4*)(Ap + q * 4) = make_float4(ap[q*4], ap[q*4+1], ap[q*4+2], ap[q*4+3]);
        *(float4*)(Hp + q * 4) = make_float4(h[q*4], h[q*4+1], h[q*4+2], h[q*4+3]);
    }
}

// ---------------- scan phase B: serial combine over chunks (in place)
__global__ void k_scanB(const float* __restrict__ Aprod, float* __restrict__ Hfin) {
    int chain = blockIdx.x * 256 + threadIdx.x;    // NSC
    float h = 0.f;
    for (int c = 0; c < NC; c++) {
        int i = c * NSC + chain;
        float a = Aprod[i], f = Hfin[i];
        Hfin[i] = h;
        h = a * h + f;
    }
}

// -------- scan phase C: rescan from start state (dt fused), gate -> y (f32)
__global__ __launch_bounds__(64) void k_scanC(const bf16* __restrict__ xb,
                                              const bf16* __restrict__ zb,
                                              const float* __restrict__ dbc,
                                              const float* __restrict__ dtw,
                                              const float* __restrict__ dtb,
                                              const float* __restrict__ a_log,
                                              const float* __restrict__ Dp,
                                              const float* __restrict__ Hstart,
                                              float* __restrict__ yb) {
    int gid = blockIdx.x * 64 + threadIdx.x;       // 131072
    int bd = gid & 1023;
    int c = gid >> 10;
    int d = bd & 511, b = bd >> 9;
    float A[16], h[16], wdt[16];
    #pragma unroll
    for (int q = 0; q < 4; q++)
        *(float4*)&wdt[q*4] = *(const float4*)(dtw + d * 16 + q * 4);
    const float* Hp = Hstart + (size_t)c * NSC + bd * 16;
    #pragma unroll
    for (int s = 0; s < 16; s++) {
        A[s] = -__expf(a_log[d * 16 + s]);
        h[s] = Hp[s];
    }
    float bdt = dtb[d];
    float Dv = Dp[d];
    int tok0 = b * SEQ + c * CL;
    const bf16* xp = xb + (size_t)tok0 * 512 + d;
    const bf16* zp = zb + (size_t)tok0 * 512 + d;
    const float* rp = dbc + (size_t)tok0 * 48;
    float* yp = yb + (size_t)tok0 * 512 + d;
    for (int t = 0; t < CL; t++) {
        float rv[48];
        #pragma unroll
        for (int q = 0; q < 12; q++) *(float4*)&rv[q*4] = *(const float4*)(rp + t * 48 + q * 4);
        float dtr = bdt;
        #pragma unroll
        for (int r = 0; r < 16; r++) dtr = fmaf(rv[r], wdt[r], dtr);
        float dtv = (dtr > 20.f) ? dtr : __logf(1.f + __expf(dtr));
        float xv = bf2f(xp[t * 512]);
        float u = dtv * xv;
        float sum = 0.f;
        #pragma unroll
        for (int s = 0; s < 16; s++) {
            float dA = __expf(dtv * A[s]);
            h[s] = fmaf(dA, h[s], u * rv[16 + s]);
            sum = fmaf(h[s], rv[32 + s], sum);
        }
        float zv = bf2f(zp[t * 512]);
        yp[t * 512] = (sum + Dv * xv) * silu(zv);
    }
}

// ---------------------------------------------------------------- lm head
__global__ void k_head(const float* __restrict__ hn, const float* __restrict__ lw,
                       float* __restrict__ out) {
    int idx = blockIdx.x * 256 + threadIdx.x;      // NTOK*20 = 81920
    int tok = idx / 20, v = idx % 20;
    const float* a = hn + (size_t)tok * 256;
    const float* w = lw + (size_t)v * 256;
    float acc = 0.f;
    for (int k = 0; k < 256; k++) acc += a[k] * w[k];
    out[idx] = acc;
}

extern "C" void kernel_launch(void* const* d_in, const int* in_sizes, int n_in,
                              void* d_out, int out_size, void* d_ws, size_t ws_size,
                              hipStream_t stream) {
    const int*   ids    = (const int*)d_in[0];
    const float* emb    = (const float*)d_in[1];
    const float* in_w   = (const float*)d_in[2];
    const float* conv_w = (const float*)d_in[3];
    const float* conv_b = (const float*)d_in[4];
    const float* x_w    = (const float*)d_in[5];
    const float* dt_w   = (const float*)d_in[6];
    const float* dt_b   = (const float*)d_in[7];
    const float* a_log  = (const float*)d_in[8];
    const float* d_skip = (const float*)d_in[9];
    const float* out_w  = (const float*)d_in[10];
    const float* norm_w = (const float*)d_in[11];
    const float* norm_f = (const float*)d_in[12];
    const float* lm_w   = (const float*)d_in[13];
    float* out = (float*)d_out;

    // ---- workspace: exactly 42,729,472 bytes (r5/r6-proven budget) ----
    char* ws = (char*)d_ws;
    float* residual = (float*)(ws + 0);            // 4 MB
    float* hn       = (float*)(ws + 4194304);      // 4 MB
    float* xh       = (float*)(ws + 8388608);      // 8 MB f32 (aliased: yb after conv)
    bf16*  zb       = (bf16*) (ws + 16777216);     // 4 MB bf16
    bf16*  xb       = (bf16*) (ws + 20971520);     // 4 MB bf16
    float* dbc      = (float*)(ws + 25165824);     // 768 KB
    float* Aprod    = (float*)(ws + 25952256);     // NC*NSC f32 = 8 MB
    float* Hfin     = (float*)(ws + 34340864);     // 8 MB -> end 42,729,472
    float* yb       = xh;

    k_embed<<<(NTOK * 256) / 256, 256, 0, stream>>>(ids, emb, residual);

    for (int i = 0; i < N_LAYER; i++) {
        k_rmsnorm<<<NTOK, 256, 0, stream>>>(residual, norm_w + i * D_MODEL, hn);
        dim3 g1(NTOK / 64, 1024 / 64);
        k_gemm1_mfma<<<g1, 256, 0, stream>>>(hn, in_w + (size_t)i * 1024 * 256, xh, zb);
        k_conv<<<(512 * NTOK / 4) / 256, 256, 0, stream>>>(
            xh, conv_w + (size_t)i * 512 * 4, conv_b + (size_t)i * 512, xb);
        k_xproj_mfma<<<NTOK / 64, 256, 0, stream>>>(
            xb, x_w + (size_t)i * 48 * 512, dbc);
        k_scanA<<<(1024 * NC) / 64, 64, 0, stream>>>(
            xb, dbc, dt_w + (size_t)i * 512 * 16, dt_b + (size_t)i * 512,
            a_log + (size_t)i * 512 * 16, Aprod, Hfin);
        k_scanB<<<NSC / 256, 256, 0, stream>>>(Aprod, Hfin);
        k_scanC<<<(1024 * NC) / 64, 64, 0, stream>>>(
            xb, zb, dbc, dt_w + (size_t)i * 512 * 16, dt_b + (size_t)i * 512,
            a_log + (size_t)i * 512 * 16, d_skip + (size_t)i * 512, Hfin, yb);
        dim3 g2(NTOK / 64, 256 / 64);
        k_gemm2_mfma<<<g2, 256, 0, stream>>>(yb, out_w + (size_t)i * 256 * 512, residual);
    }

    k_rmsnorm<<<NTOK, 256, 0, stream>>>(residual, norm_f, hn);
    k_head<<<320, 256, 0, stream>>>(hn, lm_w, out);
}

// Round 16
// 1539.238 us; speedup vs baseline: 1.8232x; 1.1396x over previous
//
#include <hip/hip_runtime.h>
#include <hip/hip_bf16.h>

#define D_MODEL 256
#define N_LAYER 16
#define VOCAB 24
#define D_INNER 512
#define D_STATE 16
#define D_CONV 4
#define DT_RANK 16
#define BATCH 2
#define SEQ 2048
#define NTOK (BATCH*SEQ)   /* 4096 */
#define EPS 1e-5f
#define NC 128             /* scan chunks per sequence */
#define CL (SEQ/NC)        /* 16 tokens per chunk */
#define NSC (BATCH*D_INNER*D_STATE)      /* 16384 scan chains */

typedef __hip_bfloat16 bf16;
typedef __attribute__((ext_vector_type(8))) short short8;
typedef __attribute__((ext_vector_type(4))) float f32x4;

__device__ __forceinline__ float silu(float v) { return v / (1.f + __expf(-v)); }
__device__ __forceinline__ float bf2f(bf16 v) { return __bfloat162float(v); }

__device__ __forceinline__ short bfr(float x) {      // f32 -> bf16 RNE
    unsigned u = __float_as_uint(x);
    return (short)((u + 0x7fffu + ((u >> 16) & 1u)) >> 16);
}

// ------------- per-layer weight pre-convert: f32 -> bf16 (one pass)
// in_w slice 262144, out_w slice 131072, x_w slice 24576 elements
__global__ void k_wcvt(const float* __restrict__ in_w, const float* __restrict__ out_w,
                       const float* __restrict__ x_w, short* __restrict__ in_wb,
                       short* __restrict__ out_wb, short* __restrict__ x_wb) {
    int idx = blockIdx.x * 256 + threadIdx.x;      // 417792 padded to 417792
    if (idx < 262144) {
        in_wb[idx] = bfr(in_w[idx]);
    } else if (idx < 262144 + 131072) {
        int j = idx - 262144;
        out_wb[j] = bfr(out_w[j]);
    } else if (idx < 262144 + 131072 + 24576) {
        int j = idx - 262144 - 131072;
        x_wb[j] = bfr(x_w[j]);
    }
}

// ---------------------------------------------------------------- embedding
__global__ void k_embed(const int* __restrict__ ids, const float* __restrict__ emb,
                        float* __restrict__ residual) {
    int idx = blockIdx.x * 256 + threadIdx.x;      // NTOK*256
    int tok = idx >> 8, c = idx & 255;
    residual[idx] = emb[ids[tok] * D_MODEL + c];
}

// ------------------------------------------- rmsnorm -> bf16 hn
__global__ void k_rmsnorm(const float* __restrict__ residual, const float* __restrict__ w,
                          bf16* __restrict__ hn) {
    __shared__ float red[256];
    int tok = blockIdx.x, c = threadIdx.x;
    float v = residual[tok * 256 + c];
    red[c] = v * v;
    __syncthreads();
    for (int st = 128; st > 0; st >>= 1) {
        if (c < st) red[c] += red[c + st];
        __syncthreads();
    }
    float scale = rsqrtf(red[0] * (1.f / 256.f) + EPS);
    hn[tok * 256 + c] = __float2bfloat16(v * scale * w[c]);
}

// ---------------- gemm1 MFMA: [NTOK,256]bf16 @ [1024,256]^T bf16 -> xh/zb bf16
// pure-copy staging (both operands pre-bf16); v_mfma_f32_16x16x32_bf16
__global__ __launch_bounds__(256) void k_gemm1_mfma(const bf16* __restrict__ Abf,
                                                    const short* __restrict__ W16,
                                                    bf16* __restrict__ xh,
                                                    bf16* __restrict__ zb) {
    __shared__ short AsL[64 * 40];   // [row][40] bf16, pad 32->40
    __shared__ short WsL[64 * 40];
    const short* A16 = (const short*)Abf;
    const int bm = blockIdx.x * 64, bn = blockIdx.y * 64;
    const int tid = threadIdx.x;
    const int wave = tid >> 6, lane = tid & 63;
    const int wm = (wave & 1) * 32, wn = (wave >> 1) * 32;
    const int quad = lane >> 4, lr = lane & 15;
    const int srow = tid >> 2, skq = (tid & 3) * 8;
    f32x4 acc[2][2] = {};
    for (int k0 = 0; k0 < 256; k0 += 32) {
        short8 a8 = *(const short8*)(A16 + (size_t)(bm + srow) * 256 + k0 + skq);
        short8 w8 = *(const short8*)(W16 + (size_t)(bn + srow) * 256 + k0 + skq);
        __syncthreads();
        *(short8*)&AsL[srow * 40 + skq] = a8;
        *(short8*)&WsL[srow * 40 + skq] = w8;
        __syncthreads();
        short8 af[2], bf[2];
        #pragma unroll
        for (int i = 0; i < 2; i++) {
            af[i] = *(const short8*)&AsL[(wm + i * 16 + lr) * 40 + quad * 8];
            bf[i] = *(const short8*)&WsL[(wn + i * 16 + lr) * 40 + quad * 8];
        }
        #pragma unroll
        for (int mi = 0; mi < 2; mi++)
            #pragma unroll
            for (int ni = 0; ni < 2; ni++)
                acc[mi][ni] = __builtin_amdgcn_mfma_f32_16x16x32_bf16(
                    af[mi], bf[ni], acc[mi][ni], 0, 0, 0);
    }
    #pragma unroll
    for (int mi = 0; mi < 2; mi++) {
        #pragma unroll
        for (int ni = 0; ni < 2; ni++) {
            int gcol = bn + wn + ni * 16 + lr;
            #pragma unroll
            for (int r = 0; r < 4; r++) {
                int grow = bm + wm + mi * 16 + quad * 4 + r;
                float v = acc[mi][ni][r];
                if (bn < 512) xh[(size_t)grow * 512 + gcol] = __float2bfloat16(v);
                else          zb[(size_t)grow * 512 + gcol - 512] = __float2bfloat16(v);
            }
        }
    }
}

// ---------------- gemm2 MFMA: residual += [NTOK,512]bf16 @ [256,512]^T bf16
__global__ __launch_bounds__(256) void k_gemm2_mfma(const bf16* __restrict__ Abf,
                                                    const short* __restrict__ W16,
                                                    float* __restrict__ residual) {
    __shared__ short AsL[64 * 40];
    __shared__ short WsL[64 * 40];
    const short* A16 = (const short*)Abf;
    const int bm = blockIdx.x * 64, bn = blockIdx.y * 64;
    const int tid = threadIdx.x;
    const int wave = tid >> 6, lane = tid & 63;
    const int wm = (wave & 1) * 32, wn = (wave >> 1) * 32;
    const int quad = lane >> 4, lr = lane & 15;
    const int srow = tid >> 2, skq = (tid & 3) * 8;
    f32x4 acc[2][2] = {};
    for (int k0 = 0; k0 < 512; k0 += 32) {
        short8 a8 = *(const short8*)(A16 + (size_t)(bm + srow) * 512 + k0 + skq);
        short8 w8 = *(const short8*)(W16 + (size_t)(bn + srow) * 512 + k0 + skq);
        __syncthreads();
        *(short8*)&AsL[srow * 40 + skq] = a8;
        *(short8*)&WsL[srow * 40 + skq] = w8;
        __syncthreads();
        short8 af[2], bf[2];
        #pragma unroll
        for (int i = 0; i < 2; i++) {
            af[i] = *(const short8*)&AsL[(wm + i * 16 + lr) * 40 + quad * 8];
            bf[i] = *(const short8*)&WsL[(wn + i * 16 + lr) * 40 + quad * 8];
        }
        #pragma unroll
        for (int mi = 0; mi < 2; mi++)
            #pragma unroll
            for (int ni = 0; ni < 2; ni++)
                acc[mi][ni] = __builtin_amdgcn_mfma_f32_16x16x32_bf16(
                    af[mi], bf[ni], acc[mi][ni], 0, 0, 0);
    }
    #pragma unroll
    for (int mi = 0; mi < 2; mi++) {
        #pragma unroll
        for (int ni = 0; ni < 2; ni++) {
            int gcol = bn + wn + ni * 16 + lr;
            #pragma unroll
            for (int r = 0; r < 4; r++) {
                int grow = bm + wm + mi * 16 + quad * 4 + r;
                size_t idx = (size_t)grow * 256 + gcol;
                residual[idx] += acc[mi][ni][r];
            }
        }
    }
}

// ---------------- depthwise conv + silu: thread = (d, 4 consecutive tokens)
__global__ void k_conv(const bf16* __restrict__ xh, const float* __restrict__ cw,
                       const float* __restrict__ cb, bf16* __restrict__ xb) {
    int gid = blockIdx.x * 256 + threadIdx.x;      // 512 * NTOK/4 = 524288
    int d = gid & 511;
    int tq = gid >> 9;                             // 0..1023
    int tok0 = tq * 4;                             // 4 | 2048: no batch crossing
    int b = tok0 >> 11, l0 = tok0 & 2047;
    float4 cwv = *(const float4*)(cw + d * 4);
    float cbv = cb[d];
    const bf16* base = xh + ((size_t)(b << 11)) * 512 + d;
    float xv[7];
    #pragma unroll
    for (int i = 0; i < 7; i++) {
        int lt = l0 - 3 + i;
        xv[i] = (lt >= 0) ? bf2f(base[(size_t)lt * 512]) : 0.f;
    }
    bf16* dst = xb + (size_t)tok0 * 512 + d;
    #pragma unroll
    for (int t = 0; t < 4; t++) {
        float acc = cbv + xv[t] * cwv.x + xv[t+1] * cwv.y + xv[t+2] * cwv.z + xv[t+3] * cwv.w;
        dst[(size_t)t * 512] = __float2bfloat16(silu(acc));
    }
}

// ---------------- x_proj MFMA: dbc[NTOK,48] = xc[NTOK,512]bf16 @ xw[48,512]^T bf16
__global__ __launch_bounds__(256) void k_xproj_mfma(const bf16* __restrict__ Abf,
                                                    const short* __restrict__ W16,
                                                    float* __restrict__ dbc) {
    __shared__ short AsL[64 * 40];
    __shared__ short WsL[64 * 40];
    const short* A16 = (const short*)Abf;
    const int bm = blockIdx.x * 64;
    const int tid = threadIdx.x;
    const int wave = tid >> 6, lane = tid & 63;
    const int wm = (wave & 1) * 32, wn = (wave >> 1) * 32;
    const int quad = lane >> 4, lr = lane & 15;
    const int srow = tid >> 2, skq = (tid & 3) * 8;
    f32x4 acc[2][2] = {};
    for (int k0 = 0; k0 < 512; k0 += 32) {
        short8 a8 = *(const short8*)(A16 + (size_t)(bm + srow) * 512 + k0 + skq);
        short8 w8;
        if (srow < 48) w8 = *(const short8*)(W16 + (size_t)srow * 512 + k0 + skq);
        __syncthreads();
        *(short8*)&AsL[srow * 40 + skq] = a8;
        if (srow < 48) *(short8*)&WsL[srow * 40 + skq] = w8;
        __syncthreads();
        short8 af[2], bf[2];
        #pragma unroll
        for (int i = 0; i < 2; i++) {
            af[i] = *(const short8*)&AsL[(wm + i * 16 + lr) * 40 + quad * 8];
            bf[i] = *(const short8*)&WsL[(wn + i * 16 + lr) * 40 + quad * 8];
        }
        #pragma unroll
        for (int mi = 0; mi < 2; mi++)
            #pragma unroll
            for (int ni = 0; ni < 2; ni++)
                acc[mi][ni] = __builtin_amdgcn_mfma_f32_16x16x32_bf16(
                    af[mi], bf[ni], acc[mi][ni], 0, 0, 0);
    }
    #pragma unroll
    for (int mi = 0; mi < 2; mi++) {
        #pragma unroll
        for (int ni = 0; ni < 2; ni++) {
            int gcol = wn + ni * 16 + lr;
            if (gcol < 48) {
                #pragma unroll
                for (int r = 0; r < 4; r++) {
                    int grow = bm + wm + mi * 16 + quad * 4 + r;
                    dbc[(size_t)grow * 48 + gcol] = acc[mi][ni][r];
                }
            }
        }
    }
}

// -------- scan phase A: thread = (b,d,chunk); dt fused; 16 s-states in regs
__global__ __launch_bounds__(64) void k_scanA(const bf16* __restrict__ xb,
                                              const float* __restrict__ dbc,
                                              const float* __restrict__ dtw,
                                              const float* __restrict__ dtb,
                                              const float* __restrict__ a_log,
                                              float* __restrict__ Aprod,
                                              float* __restrict__ Hfin) {
    int gid = blockIdx.x * 64 + threadIdx.x;       // 1024*NC = 131072
    int bd = gid & 1023;                           // d fast -> coalesced
    int c = gid >> 10;
    int d = bd & 511, b = bd >> 9;
    float A[16], h[16], ap[16], wdt[16];
    #pragma unroll
    for (int q = 0; q < 4; q++)
        *(float4*)&wdt[q*4] = *(const float4*)(dtw + d * 16 + q * 4);
    #pragma unroll
    for (int s = 0; s < 16; s++) {
        A[s] = -__expf(a_log[d * 16 + s]);
        h[s] = 0.f; ap[s] = 1.f;
    }
    float bdt = dtb[d];
    int tok0 = b * SEQ + c * CL;
    const bf16* xp = xb + (size_t)tok0 * 512 + d;
    const float* rp = dbc + (size_t)tok0 * 48;
    for (int t = 0; t < CL; t++) {
        float rv[32];
        #pragma unroll
        for (int q = 0; q < 8; q++) *(float4*)&rv[q*4] = *(const float4*)(rp + t * 48 + q * 4);
        float dtr = bdt;
        #pragma unroll
        for (int r = 0; r < 16; r++) dtr = fmaf(rv[r], wdt[r], dtr);
        float dtv = (dtr > 20.f) ? dtr : __logf(1.f + __expf(dtr));
        float u = dtv * bf2f(xp[t * 512]);
        #pragma unroll
        for (int s = 0; s < 16; s++) {
            float dA = __expf(dtv * A[s]);
            h[s] = fmaf(dA, h[s], u * rv[16 + s]);
            ap[s] *= dA;
        }
    }
    float* Ap = Aprod + (size_t)c * NSC + bd * 16;
    float* Hp = Hfin  + (size_t)c * NSC + bd * 16;
    #pragma unroll
    for (int q = 0; q < 4; q++) {
        *(float4*)(Ap + q * 4) = make_float4(ap[q*4], ap[q*4+1], ap[q*4+2], ap[q*4+3]);
        *(float4*)(Hp + q * 4) = make_float4(h[q*4], h[q*4+1], h[q*4+2], h[q*4+3]);
    }
}

// ---------------- scan phase B: serial combine over chunks (in place)
__global__ void k_scanB(const float* __restrict__ Aprod, float* __restrict__ Hfin) {
    int chain = blockIdx.x * 256 + threadIdx.x;    // NSC
    float h = 0.f;
    for (int c = 0; c < NC; c++) {
        int i = c * NSC + chain;
        float a = Aprod[i], f = Hfin[i];
        Hfin[i] = h;
        h = a * h + f;
    }
}

// -------- scan phase C: rescan from start state (dt fused), gate -> y (bf16)
__global__ __launch_bounds__(64) void k_scanC(const bf16* __restrict__ xb,
                                              const bf16* __restrict__ zb,
                                              const float* __restrict__ dbc,
                                              const float* __restrict__ dtw,
                                              const float* __restrict__ dtb,
                                              const float* __restrict__ a_log,
                                              const float* __restrict__ Dp,
                                              const float* __restrict__ Hstart,
                                              bf16* __restrict__ yb) {
    int gid = blockIdx.x * 64 + threadIdx.x;       // 131072
    int bd = gid & 1023;
    int c = gid >> 10;
    int d = bd & 511, b = bd >> 9;
    float A[16], h[16], wdt[16];
    #pragma unroll
    for (int q = 0; q < 4; q++)
        *(float4*)&wdt[q*4] = *(const float4*)(dtw + d * 16 + q * 4);
    const float* Hp = Hstart + (size_t)c * NSC + bd * 16;
    #pragma unroll
    for (int s = 0; s < 16; s++) {
        A[s] = -__expf(a_log[d * 16 + s]);
        h[s] = Hp[s];
    }
    float bdt = dtb[d];
    float Dv = Dp[d];
    int tok0 = b * SEQ + c * CL;
    const bf16* xp = xb + (size_t)tok0 * 512 + d;
    const bf16* zp = zb + (size_t)tok0 * 512 + d;
    const float* rp = dbc + (size_t)tok0 * 48;
    bf16* yp = yb + (size_t)tok0 * 512 + d;
    for (int t = 0; t < CL; t++) {
        float rv[48];
        #pragma unroll
        for (int q = 0; q < 12; q++) *(float4*)&rv[q*4] = *(const float4*)(rp + t * 48 + q * 4);
        float dtr = bdt;
        #pragma unroll
        for (int r = 0; r < 16; r++) dtr = fmaf(rv[r], wdt[r], dtr);
        float dtv = (dtr > 20.f) ? dtr : __logf(1.f + __expf(dtr));
        float xv = bf2f(xp[t * 512]);
        float u = dtv * xv;
        float sum = 0.f;
        #pragma unroll
        for (int s = 0; s < 16; s++) {
            float dA = __expf(dtv * A[s]);
            h[s] = fmaf(dA, h[s], u * rv[16 + s]);
            sum = fmaf(h[s], rv[32 + s], sum);
        }
        float zv = bf2f(zp[t * 512]);
        yp[t * 512] = __float2bfloat16((sum + Dv * xv) * silu(zv));
    }
}

// ---------------------------------------------------------------- lm head
__global__ void k_head(const bf16* __restrict__ hn, const float* __restrict__ lw,
                       float* __restrict__ out) {
    int idx = blockIdx.x * 256 + threadIdx.x;      // NTOK*20 = 81920
    int tok = idx / 20, v = idx % 20;
    const bf16* a = hn + (size_t)tok * 256;
    const float* w = lw + (size_t)v * 256;
    float acc = 0.f;
    for (int k = 0; k < 256; k++) acc += bf2f(a[k]) * w[k];
    out[idx] = acc;
}

extern "C" void kernel_launch(void* const* d_in, const int* in_sizes, int n_in,
                              void* d_out, int out_size, void* d_ws, size_t ws_size,
                              hipStream_t stream) {
    const int*   ids    = (const int*)d_in[0];
    const float* emb    = (const float*)d_in[1];
    const float* in_w   = (const float*)d_in[2];
    const float* conv_w = (const float*)d_in[3];
    const float* conv_b = (const float*)d_in[4];
    const float* x_w    = (const float*)d_in[5];
    const float* dt_w   = (const float*)d_in[6];
    const float* dt_b   = (const float*)d_in[7];
    const float* a_log  = (const float*)d_in[8];
    const float* d_skip = (const float*)d_in[9];
    const float* out_w  = (const float*)d_in[10];
    const float* norm_w = (const float*)d_in[11];
    const float* norm_f = (const float*)d_in[12];
    const float* lm_w   = (const float*)d_in[13];
    float* out = (float*)d_out;

    // ---- workspace: 37,273,600 bytes (< proven 42,729,472 budget) ----
    char* ws = (char*)d_ws;
    float* residual = (float*)(ws + 0);            // 4 MB
    bf16*  hn       = (bf16*) (ws + 4194304);      // 2 MB bf16
    bf16*  xh       = (bf16*) (ws + 6291456);      // 4 MB bf16 (alias: yb)
    bf16*  zb       = (bf16*) (ws + 10485760);     // 4 MB bf16
    bf16*  xb       = (bf16*) (ws + 14680064);     // 4 MB bf16
    float* dbc      = (float*)(ws + 18874368);     // 768 KB
    float* Aprod    = (float*)(ws + 19660800);     // 8 MB
    float* Hfin     = (float*)(ws + 28049408);     // 8 MB
    short* in_wb    = (short*)(ws + 36438016);     // 512 KB bf16 weights
    short* out_wb   = (short*)(ws + 36962304);     // 256 KB
    short* x_wb     = (short*)(ws + 37224448);     // 48 KB -> end 37,273,600
    bf16*  yb       = xh;

    k_embed<<<(NTOK * 256) / 256, 256, 0, stream>>>(ids, emb, residual);

    for (int i = 0; i < N_LAYER; i++) {
        k_wcvt<<<(262144 + 131072 + 24576) / 256, 256, 0, stream>>>(
            in_w + (size_t)i * 1024 * 256, out_w + (size_t)i * 256 * 512,
            x_w + (size_t)i * 48 * 512, in_wb, out_wb, x_wb);
        k_rmsnorm<<<NTOK, 256, 0, stream>>>(residual, norm_w + i * D_MODEL, hn);
        dim3 g1(NTOK / 64, 1024 / 64);
        k_gemm1_mfma<<<g1, 256, 0, stream>>>(hn, in_wb, xh, zb);
        k_conv<<<(512 * NTOK / 4) / 256, 256, 0, stream>>>(
            xh, conv_w + (size_t)i * 512 * 4, conv_b + (size_t)i * 512, xb);
        k_xproj_mfma<<<NTOK / 64, 256, 0, stream>>>(xb, x_wb, dbc);
        k_scanA<<<(1024 * NC) / 64, 64, 0, stream>>>(
            xb, dbc, dt_w + (size_t)i * 512 * 16, dt_b + (size_t)i * 512,
            a_log + (size_t)i * 512 * 16, Aprod, Hfin);
        k_scanB<<<NSC / 256, 256, 0, stream>>>(Aprod, Hfin);
        k_scanC<<<(1024 * NC) / 64, 64, 0, stream>>>(
            xb, zb, dbc, dt_w + (size_t)i * 512 * 16, dt_b + (size_t)i * 512,
            a_log + (size_t)i * 512 * 16, d_skip + (size_t)i * 512, Hfin, yb);
        dim3 g2(NTOK / 64, 256 / 64);
        k_gemm2_mfma<<<g2, 256, 0, stream>>>(yb, out_wb, residual);
    }

    k_rmsnorm<<<NTOK, 256, 0, stream>>>(residual, norm_f, hn);
    k_head<<<320, 256, 0, stream>>>(hn, lm_w, out);
}

// Round 17
// 1508.389 us; speedup vs baseline: 1.8605x; 1.0205x over previous
//
#include <hip/hip_runtime.h>
#include <hip/hip_bf16.h>

#define D_MODEL 256
#define N_LAYER 16
#define VOCAB 24
#define D_INNER 512
#define D_STATE 16
#define D_CONV 4
#define DT_RANK 16
#define BATCH 2
#define SEQ 2048
#define NTOK (BATCH*SEQ)   /* 4096 */
#define EPS 1e-5f
#define NC 128             /* scan chunks per sequence */
#define CL (SEQ/NC)        /* 16 tokens per chunk */
#define NSC (BATCH*D_INNER*D_STATE)      /* 16384 scan chains */

typedef __hip_bfloat16 bf16;
typedef __attribute__((ext_vector_type(8))) short short8;
typedef __attribute__((ext_vector_type(4))) float f32x4;

__device__ __forceinline__ float silu(float v) { return v / (1.f + __expf(-v)); }
__device__ __forceinline__ float bf2f(bf16 v) { return __bfloat162float(v); }

__device__ __forceinline__ short bfr(float x) {      // f32 -> bf16 RNE
    unsigned u = __float_as_uint(x);
    return (short)((u + 0x7fffu + ((u >> 16) & 1u)) >> 16);
}
__device__ __forceinline__ float bfround(float x) {  // f32 -> bf16 -> f32
    unsigned u = __float_as_uint(x);
    unsigned r = ((u + 0x7fffu + ((u >> 16) & 1u)) >> 16) << 16;
    return __uint_as_float(r);
}

// ------------- ALL-layer weight pre-convert: f32 -> bf16, one pass
// in_w 16*262144, out_w 16*131072, x_w 16*24576 elements
__global__ void k_wcvt_all(const float* __restrict__ in_w, const float* __restrict__ out_w,
                           const float* __restrict__ x_w, short* __restrict__ in_wb,
                           short* __restrict__ out_wb, short* __restrict__ x_wb) {
    int idx = blockIdx.x * 256 + threadIdx.x;      // 6,684,672 total
    if (idx < 4194304) {
        in_wb[idx] = bfr(in_w[idx]);
    } else if (idx < 4194304 + 2097152) {
        int j = idx - 4194304;
        out_wb[j] = bfr(out_w[j]);
    } else {
        int j = idx - 4194304 - 2097152;           // < 393216
        x_wb[j] = bfr(x_w[j]);
    }
}

// ---------------------------------------------------------------- embedding
__global__ void k_embed(const int* __restrict__ ids, const float* __restrict__ emb,
                        float* __restrict__ residual) {
    int idx = blockIdx.x * 256 + threadIdx.x;      // NTOK*256
    int tok = idx >> 8, c = idx & 255;
    residual[idx] = emb[ids[tok] * D_MODEL + c];
}

// ------------------------------------------- rmsnorm -> bf16 hn
__global__ void k_rmsnorm(const float* __restrict__ residual, const float* __restrict__ w,
                          bf16* __restrict__ hn) {
    __shared__ float red[256];
    int tok = blockIdx.x, c = threadIdx.x;
    float v = residual[tok * 256 + c];
    red[c] = v * v;
    __syncthreads();
    for (int st = 128; st > 0; st >>= 1) {
        if (c < st) red[c] += red[c + st];
        __syncthreads();
    }
    float scale = rsqrtf(red[0] * (1.f / 256.f) + EPS);
    hn[tok * 256 + c] = __float2bfloat16(v * scale * w[c]);
}

// ---------------- gemm1 MFMA: [NTOK,256]bf16 @ [1024,256]^T bf16 -> xh/zb bf16
__global__ __launch_bounds__(256) void k_gemm1_mfma(const bf16* __restrict__ Abf,
                                                    const short* __restrict__ W16,
                                                    bf16* __restrict__ xh,
                                                    bf16* __restrict__ zb) {
    __shared__ short AsL[64 * 40];   // [row][40] bf16, pad 32->40
    __shared__ short WsL[64 * 40];
    const short* A16 = (const short*)Abf;
    const int bm = blockIdx.x * 64, bn = blockIdx.y * 64;
    const int tid = threadIdx.x;
    const int wave = tid >> 6, lane = tid & 63;
    const int wm = (wave & 1) * 32, wn = (wave >> 1) * 32;
    const int quad = lane >> 4, lr = lane & 15;
    const int srow = tid >> 2, skq = (tid & 3) * 8;
    f32x4 acc[2][2] = {};
    for (int k0 = 0; k0 < 256; k0 += 32) {
        short8 a8 = *(const short8*)(A16 + (size_t)(bm + srow) * 256 + k0 + skq);
        short8 w8 = *(const short8*)(W16 + (size_t)(bn + srow) * 256 + k0 + skq);
        __syncthreads();
        *(short8*)&AsL[srow * 40 + skq] = a8;
        *(short8*)&WsL[srow * 40 + skq] = w8;
        __syncthreads();
        short8 af[2], bf[2];
        #pragma unroll
        for (int i = 0; i < 2; i++) {
            af[i] = *(const short8*)&AsL[(wm + i * 16 + lr) * 40 + quad * 8];
            bf[i] = *(const short8*)&WsL[(wn + i * 16 + lr) * 40 + quad * 8];
        }
        #pragma unroll
        for (int mi = 0; mi < 2; mi++)
            #pragma unroll
            for (int ni = 0; ni < 2; ni++)
                acc[mi][ni] = __builtin_amdgcn_mfma_f32_16x16x32_bf16(
                    af[mi], bf[ni], acc[mi][ni], 0, 0, 0);
    }
    #pragma unroll
    for (int mi = 0; mi < 2; mi++) {
        #pragma unroll
        for (int ni = 0; ni < 2; ni++) {
            int gcol = bn + wn + ni * 16 + lr;
            #pragma unroll
            for (int r = 0; r < 4; r++) {
                int grow = bm + wm + mi * 16 + quad * 4 + r;
                float v = acc[mi][ni][r];
                if (bn < 512) xh[(size_t)grow * 512 + gcol] = __float2bfloat16(v);
                else          zb[(size_t)grow * 512 + gcol - 512] = __float2bfloat16(v);
            }
        }
    }
}

// ---------------- gemm2 MFMA: residual += [NTOK,512]bf16 @ [256,512]^T bf16
__global__ __launch_bounds__(256) void k_gemm2_mfma(const bf16* __restrict__ Abf,
                                                    const short* __restrict__ W16,
                                                    float* __restrict__ residual) {
    __shared__ short AsL[64 * 40];
    __shared__ short WsL[64 * 40];
    const short* A16 = (const short*)Abf;
    const int bm = blockIdx.x * 64, bn = blockIdx.y * 64;
    const int tid = threadIdx.x;
    const int wave = tid >> 6, lane = tid & 63;
    const int wm = (wave & 1) * 32, wn = (wave >> 1) * 32;
    const int quad = lane >> 4, lr = lane & 15;
    const int srow = tid >> 2, skq = (tid & 3) * 8;
    f32x4 acc[2][2] = {};
    for (int k0 = 0; k0 < 512; k0 += 32) {
        short8 a8 = *(const short8*)(A16 + (size_t)(bm + srow) * 512 + k0 + skq);
        short8 w8 = *(const short8*)(W16 + (size_t)(bn + srow) * 512 + k0 + skq);
        __syncthreads();
        *(short8*)&AsL[srow * 40 + skq] = a8;
        *(short8*)&WsL[srow * 40 + skq] = w8;
        __syncthreads();
        short8 af[2], bf[2];
        #pragma unroll
        for (int i = 0; i < 2; i++) {
            af[i] = *(const short8*)&AsL[(wm + i * 16 + lr) * 40 + quad * 8];
            bf[i] = *(const short8*)&WsL[(wn + i * 16 + lr) * 40 + quad * 8];
        }
        #pragma unroll
        for (int mi = 0; mi < 2; mi++)
            #pragma unroll
            for (int ni = 0; ni < 2; ni++)
                acc[mi][ni] = __builtin_amdgcn_mfma_f32_16x16x32_bf16(
                    af[mi], bf[ni], acc[mi][ni], 0, 0, 0);
    }
    #pragma unroll
    for (int mi = 0; mi < 2; mi++) {
        #pragma unroll
        for (int ni = 0; ni < 2; ni++) {
            int gcol = bn + wn + ni * 16 + lr;
            #pragma unroll
            for (int r = 0; r < 4; r++) {
                int grow = bm + wm + mi * 16 + quad * 4 + r;
                size_t idx = (size_t)grow * 256 + gcol;
                residual[idx] += acc[mi][ni][r];
            }
        }
    }
}

// ---------------- depthwise conv + silu: thread = (d, 4 consecutive tokens)
__global__ void k_conv(const bf16* __restrict__ xh, const float* __restrict__ cw,
                       const float* __restrict__ cb, bf16* __restrict__ xb) {
    int gid = blockIdx.x * 256 + threadIdx.x;      // 512 * NTOK/4 = 524288
    int d = gid & 511;
    int tq = gid >> 9;                             // 0..1023
    int tok0 = tq * 4;                             // 4 | 2048: no batch crossing
    int b = tok0 >> 11, l0 = tok0 & 2047;
    float4 cwv = *(const float4*)(cw + d * 4);
    float cbv = cb[d];
    const bf16* base = xh + ((size_t)(b << 11)) * 512 + d;
    float xv[7];
    #pragma unroll
    for (int i = 0; i < 7; i++) {
        int lt = l0 - 3 + i;
        xv[i] = (lt >= 0) ? bf2f(base[(size_t)lt * 512]) : 0.f;
    }
    bf16* dst = xb + (size_t)tok0 * 512 + d;
    #pragma unroll
    for (int t = 0; t < 4; t++) {
        float acc = cbv + xv[t] * cwv.x + xv[t+1] * cwv.y + xv[t+2] * cwv.z + xv[t+3] * cwv.w;
        dst[(size_t)t * 512] = __float2bfloat16(silu(acc));
    }
}

// ---------------- x_proj MFMA: dbc[NTOK,48] = xc[NTOK,512]bf16 @ xw[48,512]^T bf16
__global__ __launch_bounds__(256) void k_xproj_mfma(const bf16* __restrict__ Abf,
                                                    const short* __restrict__ W16,
                                                    float* __restrict__ dbc) {
    __shared__ short AsL[64 * 40];
    __shared__ short WsL[64 * 40];
    const short* A16 = (const short*)Abf;
    const int bm = blockIdx.x * 64;
    const int tid = threadIdx.x;
    const int wave = tid >> 6, lane = tid & 63;
    const int wm = (wave & 1) * 32, wn = (wave >> 1) * 32;
    const int quad = lane >> 4, lr = lane & 15;
    const int srow = tid >> 2, skq = (tid & 3) * 8;
    f32x4 acc[2][2] = {};
    for (int k0 = 0; k0 < 512; k0 += 32) {
        short8 a8 = *(const short8*)(A16 + (size_t)(bm + srow) * 512 + k0 + skq);
        short8 w8;
        if (srow < 48) w8 = *(const short8*)(W16 + (size_t)srow * 512 + k0 + skq);
        __syncthreads();
        *(short8*)&AsL[srow * 40 + skq] = a8;
        if (srow < 48) *(short8*)&WsL[srow * 40 + skq] = w8;
        __syncthreads();
        short8 af[2], bf[2];
        #pragma unroll
        for (int i = 0; i < 2; i++) {
            af[i] = *(const short8*)&AsL[(wm + i * 16 + lr) * 40 + quad * 8];
            bf[i] = *(const short8*)&WsL[(wn + i * 16 + lr) * 40 + quad * 8];
        }
        #pragma unroll
        for (int mi = 0; mi < 2; mi++)
            #pragma unroll
            for (int ni = 0; ni < 2; ni++)
                acc[mi][ni] = __builtin_amdgcn_mfma_f32_16x16x32_bf16(
                    af[mi], bf[ni], acc[mi][ni], 0, 0, 0);
    }
    #pragma unroll
    for (int mi = 0; mi < 2; mi++) {
        #pragma unroll
        for (int ni = 0; ni < 2; ni++) {
            int gcol = wn + ni * 16 + lr;
            if (gcol < 48) {
                #pragma unroll
                for (int r = 0; r < 4; r++) {
                    int grow = bm + wm + mi * 16 + quad * 4 + r;
                    dbc[(size_t)grow * 48 + gcol] = acc[mi][ni][r];
                }
            }
        }
    }
}

// -------- scan phase A: thread = (b,d,chunk); computes dt (softplus) once,
// EXPORTS it (bf16) for scanC; 16 s-states in registers
__global__ __launch_bounds__(64) void k_scanA(const bf16* __restrict__ xb,
                                              const float* __restrict__ dbc,
                                              const float* __restrict__ dtw,
                                              const float* __restrict__ dtb,
                                              const float* __restrict__ a_log,
                                              bf16* __restrict__ dtout,
                                              float* __restrict__ Aprod,
                                              float* __restrict__ Hfin) {
    int gid = blockIdx.x * 64 + threadIdx.x;       // 1024*NC = 131072
    int bd = gid & 1023;                           // d fast -> coalesced
    int c = gid >> 10;
    int d = bd & 511, b = bd >> 9;
    float A[16], h[16], ap[16], wdt[16];
    #pragma unroll
    for (int q = 0; q < 4; q++)
        *(float4*)&wdt[q*4] = *(const float4*)(dtw + d * 16 + q * 4);
    #pragma unroll
    for (int s = 0; s < 16; s++) {
        A[s] = -__expf(a_log[d * 16 + s]);
        h[s] = 0.f; ap[s] = 1.f;
    }
    float bdt = dtb[d];
    int tok0 = b * SEQ + c * CL;
    const bf16* xp = xb + (size_t)tok0 * 512 + d;
    const float* rp = dbc + (size_t)tok0 * 48;
    bf16* dtp = dtout + (size_t)tok0 * 512 + d;
    for (int t = 0; t < CL; t++) {
        float rv[32];
        #pragma unroll
        for (int q = 0; q < 8; q++) *(float4*)&rv[q*4] = *(const float4*)(rp + t * 48 + q * 4);
        float dtr = bdt;
        #pragma unroll
        for (int r = 0; r < 16; r++) dtr = fmaf(rv[r], wdt[r], dtr);
        float dtv = (dtr > 20.f) ? dtr : __logf(1.f + __expf(dtr));
        dtv = bfround(dtv);                        // use the SAME value scanC will read
        dtp[t * 512] = __float2bfloat16(dtv);
        float u = dtv * bf2f(xp[t * 512]);
        #pragma unroll
        for (int s = 0; s < 16; s++) {
            float dA = __expf(dtv * A[s]);
            h[s] = fmaf(dA, h[s], u * rv[16 + s]);
            ap[s] *= dA;
        }
    }
    float* Ap = Aprod + (size_t)c * NSC + bd * 16;
    float* Hp = Hfin  + (size_t)c * NSC + bd * 16;
    #pragma unroll
    for (int q = 0; q < 4; q++) {
        *(float4*)(Ap + q * 4) = make_float4(ap[q*4], ap[q*4+1], ap[q*4+2], ap[q*4+3]);
        *(float4*)(Hp + q * 4) = make_float4(h[q*4], h[q*4+1], h[q*4+2], h[q*4+3]);
    }
}

// ---------------- scan phase B: serial combine over chunks (in place)
__global__ void k_scanB(const float* __restrict__ Aprod, float* __restrict__ Hfin) {
    int chain = blockIdx.x * 256 + threadIdx.x;    // NSC
    float h = 0.f;
    for (int c = 0; c < NC; c++) {
        int i = c * NSC + chain;
        float a = Aprod[i], f = Hfin[i];
        Hfin[i] = h;
        h = a * h + f;
    }
}

// -------- scan phase C: rescan from start state using PRECOMPUTED dt
__global__ __launch_bounds__(64) void k_scanC(const bf16* __restrict__ xb,
                                              const bf16* __restrict__ zb,
                                              const bf16* __restrict__ dtin,
                                              const float* __restrict__ dbc,
                                              const float* __restrict__ a_log,
                                              const float* __restrict__ Dp,
                                              const float* __restrict__ Hstart,
                                              bf16* __restrict__ yb) {
    int gid = blockIdx.x * 64 + threadIdx.x;       // 131072
    int bd = gid & 1023;
    int c = gid >> 10;
    int d = bd & 511, b = bd >> 9;
    float A[16], h[16];
    const float* Hp = Hstart + (size_t)c * NSC + bd * 16;
    #pragma unroll
    for (int s = 0; s < 16; s++) {
        A[s] = -__expf(a_log[d * 16 + s]);
        h[s] = Hp[s];
    }
    float Dv = Dp[d];
    int tok0 = b * SEQ + c * CL;
    const bf16* xp = xb + (size_t)tok0 * 512 + d;
    const bf16* zp = zb + (size_t)tok0 * 512 + d;
    const bf16* dtp = dtin + (size_t)tok0 * 512 + d;
    const float* rp = dbc + (size_t)tok0 * 48 + 16;   // B at +0, C at +16
    bf16* yp = yb + (size_t)tok0 * 512 + d;
    for (int t = 0; t < CL; t++) {
        float rv[32];
        #pragma unroll
        for (int q = 0; q < 8; q++) *(float4*)&rv[q*4] = *(const float4*)(rp + t * 48 + q * 4);
        float dtv = bf2f(dtp[t * 512]);
        float xv = bf2f(xp[t * 512]);
        float u = dtv * xv;
        float sum = 0.f;
        #pragma unroll
        for (int s = 0; s < 16; s++) {
            float dA = __expf(dtv * A[s]);
            h[s] = fmaf(dA, h[s], u * rv[s]);
            sum = fmaf(h[s], rv[16 + s], sum);
        }
        float zv = bf2f(zp[t * 512]);
        yp[t * 512] = __float2bfloat16((sum + Dv * xv) * silu(zv));
    }
}

// ---------------------------------------------------------------- lm head
__global__ void k_head(const bf16* __restrict__ hn, const float* __restrict__ lw,
                       float* __restrict__ out) {
    int idx = blockIdx.x * 256 + threadIdx.x;      // NTOK*20 = 81920
    int tok = idx / 20, v = idx % 20;
    const bf16* a = hn + (size_t)tok * 256;
    const float* w = lw + (size_t)v * 256;
    float acc = 0.f;
    for (int k = 0; k < 256; k++) acc += bf2f(a[k]) * w[k];
    out[idx] = acc;
}

extern "C" void kernel_launch(void* const* d_in, const int* in_sizes, int n_in,
                              void* d_out, int out_size, void* d_ws, size_t ws_size,
                              hipStream_t stream) {
    const int*   ids    = (const int*)d_in[0];
    const float* emb    = (const float*)d_in[1];
    const float* in_w   = (const float*)d_in[2];
    const float* conv_w = (const float*)d_in[3];
    const float* conv_b = (const float*)d_in[4];
    const float* x_w    = (const float*)d_in[5];
    const float* dt_w   = (const float*)d_in[6];
    const float* dt_b   = (const float*)d_in[7];
    const float* a_log  = (const float*)d_in[8];
    const float* d_skip = (const float*)d_in[9];
    const float* out_w  = (const float*)d_in[10];
    const float* norm_w = (const float*)d_in[11];
    const float* norm_f = (const float*)d_in[12];
    const float* lm_w   = (const float*)d_in[13];
    float* out = (float*)d_out;

    // ---- workspace: 54,001,664 bytes (ws_size ~268 MB per r16 WRITE_SIZE) ----
    char* ws = (char*)d_ws;
    float* residual = (float*)(ws + 0);            // 4 MB
    bf16*  hn       = (bf16*) (ws + 4194304);      // 2 MB
    bf16*  xh       = (bf16*) (ws + 6291456);      // 4 MB (alias: yb)
    bf16*  zb       = (bf16*) (ws + 10485760);     // 4 MB
    bf16*  xb       = (bf16*) (ws + 14680064);     // 4 MB
    float* dbc      = (float*)(ws + 18874368);     // 768 KB
    bf16*  dtbuf    = (bf16*) (ws + 19660800);     // 4 MB
    float* Aprod    = (float*)(ws + 23855104);     // 8 MB
    float* Hfin     = (float*)(ws + 32243712);     // 8 MB
    short* in_wb    = (short*)(ws + 40632320);     // 8 MB  (16 layers bf16)
    short* out_wb   = (short*)(ws + 49020928);     // 4 MB
    short* x_wb     = (short*)(ws + 53215232);     // 768 KB -> end 54,001,664
    bf16*  yb       = xh;

    k_wcvt_all<<<6684672 / 256, 256, 0, stream>>>(in_w, out_w, x_w, in_wb, out_wb, x_wb);
    k_embed<<<(NTOK * 256) / 256, 256, 0, stream>>>(ids, emb, residual);

    for (int i = 0; i < N_LAYER; i++) {
        k_rmsnorm<<<NTOK, 256, 0, stream>>>(residual, norm_w + i * D_MODEL, hn);
        dim3 g1(NTOK / 64, 1024 / 64);
        k_gemm1_mfma<<<g1, 256, 0, stream>>>(hn, in_wb + (size_t)i * 262144, xh, zb);
        k_conv<<<(512 * NTOK / 4) / 256, 256, 0, stream>>>(
            xh, conv_w + (size_t)i * 512 * 4, conv_b + (size_t)i * 512, xb);
        k_xproj_mfma<<<NTOK / 64, 256, 0, stream>>>(xb, x_wb + (size_t)i * 24576, dbc);
        k_scanA<<<(1024 * NC) / 64, 64, 0, stream>>>(
            xb, dbc, dt_w + (size_t)i * 512 * 16, dt_b + (size_t)i * 512,
            a_log + (size_t)i * 512 * 16, dtbuf, Aprod, Hfin);
        k_scanB<<<NSC / 256, 256, 0, stream>>>(Aprod, Hfin);
        k_scanC<<<(1024 * NC) / 64, 64, 0, stream>>>(
            xb, zb, dtbuf, dbc, a_log + (size_t)i * 512 * 16,
            d_skip + (size_t)i * 512, Hfin, yb);
        dim3 g2(NTOK / 64, 256 / 64);
        k_gemm2_mfma<<<g2, 256, 0, stream>>>(yb, out_wb + (size_t)i * 131072, residual);
    }

    k_rmsnorm<<<NTOK, 256, 0, stream>>>(residual, norm_f, hn);
    k_head<<<320, 256, 0, stream>>>(hn, lm_w, out);
}